// Round 3
// baseline (1432.521 us; speedup 1.0000x reference)
//
#include <hip/hip_runtime.h>
#include <hip/hip_bf16.h>
#include <cmath>

#define B_    16
#define L_    2048
#define T_    32768   // B_*L_
#define DM_   128
#define DI_   256
#define DXBC_ 384
#define DS_   64
#define HD_   64
#define NH_   4
#define NC_   32      // chunks per sequence (L_/64)

typedef __hip_bfloat16 bf16;

__device__ __forceinline__ float b2f(bf16 v) { return __bfloat162float(v); }
__device__ __forceinline__ bf16  f2b(float f) { return __float2bfloat16(f); }
__device__ __forceinline__ float sigmoidf_(float x) { return 1.f / (1.f + expf(-x)); }
__device__ __forceinline__ float softplusf_(float x) { return (x > 20.f) ? x : log1pf(expf(x)); }
// decay exp: argument is mathematically <= 0; clamp kills any speculative inf
__device__ __forceinline__ float expneg_(float x) { return expf(fminf(x, 0.f)); }

// ---------------------------------------------------------------------------
// K1: in_proj GEMM (x @ Wi^T) fused with causal conv1d (+bias, SiLU) for the
// xBC columns and softplus(+dt_bias) for the dt columns.
// grid: (512 row-tiles of 64 tokens, 11 col-tiles of 64, 2 dirs), block 256.
// Backward direction reads x in flipped time order; everything downstream is
// stored in processing-time order.
// ---------------------------------------------------------------------------
__global__ __launch_bounds__(256) void k_inproj(
    const float* __restrict__ x,
    const float* __restrict__ WiF, const float* __restrict__ WiB,
    const float* __restrict__ cwF, const float* __restrict__ cbF,
    const float* __restrict__ cwB, const float* __restrict__ cbB,
    const float* __restrict__ dtbF, const float* __restrict__ dtbB,
    bf16* __restrict__ Z, bf16* __restrict__ XBC, float* __restrict__ DTV)
{
    const int tid = threadIdx.x;
    const int dir = blockIdx.z;
    const float* Wi = dir ? WiB : WiF;
    const int t0 = blockIdx.x * 64;
    const int batch = t0 >> 11;
    const int l0 = t0 & (L_ - 1);
    const int ytile = blockIdx.y;
    const int c0 = ytile * 64;
    const bool is_dt  = (ytile == 10);
    const bool is_xbc = (ytile >= 4) && (ytile <= 9);
    const int ncols = is_dt ? 4 : 64;

    __shared__ __align__(16) float xs[67][68];   // rows l0-3 .. l0+63, one 64-wide k-half
    __shared__ __align__(16) float ws[64][68];
    __shared__ float raws[67][65];               // raw GEMM results for conv (xBC tiles)

    const int tr = tid >> 4;    // 0..15 -> output rows tr*4 + i
    const int tc = tid & 15;    // output cols tc + 16*j (cyclic)
    float acc[4][4] = {{0.f, 0.f, 0.f, 0.f}, {0.f, 0.f, 0.f, 0.f},
                       {0.f, 0.f, 0.f, 0.f}, {0.f, 0.f, 0.f, 0.f}};
    float sacc = 0.f;   // halo accumulator (xBC) or dt accumulator (dt tile)

    for (int kt = 0; kt < 2; ++kt) {
        const int k0 = kt * 64;
        __syncthreads();
        for (int i = tid; i < 67 * 64; i += 256) {
            int r = i >> 6, k = i & 63;
            int l = l0 - 3 + r;
            float v = 0.f;
            if (l >= 0) {
                int sl = dir ? (L_ - 1 - l) : l;
                v = x[((size_t)batch * L_ + sl) * DM_ + k0 + k];
            }
            xs[r][k] = v;
        }
        for (int i = tid; i < ncols * 64; i += 256) {
            int r = i >> 6, k = i & 63;
            ws[r][k] = Wi[(size_t)(c0 + r) * DM_ + k0 + k];
        }
        __syncthreads();

        if (is_dt) {
            int r = tid >> 2, cc = tid & 3;
            for (int k = 0; k < 64; ++k) sacc += xs[3 + r][k] * ws[cc][k];
        } else {
            for (int k = 0; k < 64; k += 4) {
                float A_[4][4], Bv[4][4];
#pragma unroll
                for (int i = 0; i < 4; ++i) {
                    float4 t = *(const float4*)&xs[3 + tr * 4 + i][k];
                    A_[i][0] = t.x; A_[i][1] = t.y; A_[i][2] = t.z; A_[i][3] = t.w;
                }
#pragma unroll
                for (int j = 0; j < 4; ++j) {
                    float4 t = *(const float4*)&ws[tc + 16 * j][k];
                    Bv[j][0] = t.x; Bv[j][1] = t.y; Bv[j][2] = t.z; Bv[j][3] = t.w;
                }
#pragma unroll
                for (int i = 0; i < 4; ++i)
#pragma unroll
                    for (int j = 0; j < 4; ++j)
#pragma unroll
                        for (int q = 0; q < 4; ++q)
                            acc[i][j] += A_[i][q] * Bv[j][q];
            }
            if (is_xbc && tid < 192) {   // conv halo rows (tokens l0-3..l0-1)
                int r = tid >> 6, cc = tid & 63;
                for (int k = 0; k < 64; ++k) sacc += xs[r][k] * ws[cc][k];
            }
        }
    }

    if (is_dt) {
        const float* dtb = dir ? dtbB : dtbF;
        int r = tid >> 2, cc = tid & 3;
        DTV[((size_t)dir * T_ + t0 + r) * NH_ + cc] = softplusf_(sacc + dtb[cc]);
        return;
    }
    if (!is_xbc) {  // z columns
#pragma unroll
        for (int i = 0; i < 4; ++i)
#pragma unroll
            for (int j = 0; j < 4; ++j)
                Z[((size_t)dir * T_ + t0 + tr * 4 + i) * DI_ + c0 + tc + 16 * j] = f2b(acc[i][j]);
        return;
    }
    // xBC columns: stage raw GEMM results, then conv + SiLU
#pragma unroll
    for (int i = 0; i < 4; ++i)
#pragma unroll
        for (int j = 0; j < 4; ++j)
            raws[3 + tr * 4 + i][tc + 16 * j] = acc[i][j];
    if (tid < 192) raws[tid >> 6][tid & 63] = sacc;
    __syncthreads();

    const float* cw = dir ? cwB : cwF;
    const float* cb = dir ? cbB : cbF;
    const int ch0 = c0 - 256;
    for (int i = tid; i < 64 * 64; i += 256) {
        int r = i >> 6, cc = i & 63;
        int ch = ch0 + cc;
        float s = cb[ch];
#pragma unroll
        for (int k = 0; k < 4; ++k) s += raws[r + k][cc] * cw[ch * 4 + k];
        s = s * sigmoidf_(s);
        XBC[((size_t)dir * T_ + t0 + r) * DXBC_ + ch] = f2b(s);
    }
}

// ---------------------------------------------------------------------------
// K2: per (chunk, b, h, dir): diag block Yd = (L ∘ C B^T) Xdt + D*x, and
// chunk states st[p][n] = sum_l dec[l] Xdt[l][p] B[l][n].
// grid: (32, 64, 2), block 256.
// ---------------------------------------------------------------------------
__global__ __launch_bounds__(256) void k_chunkdiag(
    const bf16* __restrict__ XBC, const float* __restrict__ DTV,
    const float* __restrict__ AlF, const float* __restrict__ AlB,
    const float* __restrict__ DpF, const float* __restrict__ DpB,
    bf16* __restrict__ Y, bf16* __restrict__ ST, float* __restrict__ CDb)
{
    const int tid = threadIdx.x;
    const int c = blockIdx.x;
    const int b = blockIdx.y >> 2;
    const int h = blockIdx.y & 3;
    const int dir = blockIdx.z;
    const float Ah = -expf((dir ? AlB : AlF)[h]);
    const float Dh = (dir ? DpB : DpF)[h];
    const int t0 = b * L_ + c * 64;

    __shared__ float Bs[64][65];
    __shared__ float Cs[64][65];   // reused as M after G is computed
    __shared__ float Xs[64][65];   // Xdt, later dec-scaled in place
    __shared__ float dts[64];
    __shared__ float Acs[64];

    if (tid < 64) dts[tid] = DTV[((size_t)dir * T_ + t0 + tid) * NH_ + h];
    __syncthreads();
    if (tid == 0) {
        float r = 0.f;
        for (int l = 0; l < 64; ++l) { r += dts[l] * Ah; Acs[l] = r; }
    }
    for (int i = tid; i < 4096; i += 256) {
        int l = i >> 6, n = i & 63;
        size_t base = ((size_t)dir * T_ + t0 + l) * DXBC_;
        Bs[l][n] = b2f(XBC[base + 256 + n]);
        Cs[l][n] = b2f(XBC[base + 320 + n]);
        Xs[l][n] = b2f(XBC[base + h * HD_ + n]) * dts[l];
    }
    __syncthreads();

    const int tr = tid >> 4, tc = tid & 15;
    // G = C B^T
    float g[4][4] = {{0.f, 0.f, 0.f, 0.f}, {0.f, 0.f, 0.f, 0.f},
                     {0.f, 0.f, 0.f, 0.f}, {0.f, 0.f, 0.f, 0.f}};
    for (int n = 0; n < 64; ++n) {
        float cv[4], bv[4];
#pragma unroll
        for (int i = 0; i < 4; ++i) cv[i] = Cs[tr * 4 + i][n];
#pragma unroll
        for (int j = 0; j < 4; ++j) bv[j] = Bs[tc + 16 * j][n];
#pragma unroll
        for (int i = 0; i < 4; ++i)
#pragma unroll
            for (int j = 0; j < 4; ++j) g[i][j] += cv[i] * bv[j];
    }
    __syncthreads();   // all G reads of Cs done; reuse Cs as M
#pragma unroll
    for (int i = 0; i < 4; ++i)
#pragma unroll
        for (int j = 0; j < 4; ++j) {
            int l = tr * 4 + i, s = tc + 16 * j;
            Cs[l][s] = (s <= l) ? g[i][j] * expneg_(Acs[l] - Acs[s]) : 0.f;
        }
    __syncthreads();
    // Yd = M @ Xdt
    float acc[4][4] = {{0.f, 0.f, 0.f, 0.f}, {0.f, 0.f, 0.f, 0.f},
                       {0.f, 0.f, 0.f, 0.f}, {0.f, 0.f, 0.f, 0.f}};
    for (int s = 0; s < 64; ++s) {
        float mv[4], xv[4];
#pragma unroll
        for (int i = 0; i < 4; ++i) mv[i] = Cs[tr * 4 + i][s];
#pragma unroll
        for (int j = 0; j < 4; ++j) xv[j] = Xs[s][tc + 16 * j];
#pragma unroll
        for (int i = 0; i < 4; ++i)
#pragma unroll
            for (int j = 0; j < 4; ++j) acc[i][j] += mv[i] * xv[j];
    }
#pragma unroll
    for (int i = 0; i < 4; ++i)
#pragma unroll
        for (int j = 0; j < 4; ++j) {
            int l = tr * 4 + i, p = tc + 16 * j;
            size_t tI = (size_t)dir * T_ + t0 + l;
            float xraw = b2f(XBC[tI * DXBC_ + h * HD_ + p]);
            Y[tI * DI_ + h * HD_ + p] = f2b(acc[i][j] + Dh * xraw);
        }
    __syncthreads();
    const float alast = Acs[63];
    for (int i = tid; i < 4096; i += 256) {
        int l = i >> 6;
        Xs[l][i & 63] *= expneg_(alast - Acs[l]);
    }
    __syncthreads();
    // st[p][n] = sum_l XdtDec[l][p] * B[l][n]
    float st[4][4] = {{0.f, 0.f, 0.f, 0.f}, {0.f, 0.f, 0.f, 0.f},
                      {0.f, 0.f, 0.f, 0.f}, {0.f, 0.f, 0.f, 0.f}};
    for (int l = 0; l < 64; ++l) {
        float xv[4], bv[4];
#pragma unroll
        for (int i = 0; i < 4; ++i) xv[i] = Xs[l][tr * 4 + i];
#pragma unroll
        for (int j = 0; j < 4; ++j) bv[j] = Bs[l][tc + 16 * j];
#pragma unroll
        for (int i = 0; i < 4; ++i)
#pragma unroll
            for (int j = 0; j < 4; ++j) st[i][j] += xv[i] * bv[j];
    }
    size_t sb = ((((size_t)dir * B_ + b) * NC_ + c) * NH_ + h) * 4096;
#pragma unroll
    for (int i = 0; i < 4; ++i)
#pragma unroll
        for (int j = 0; j < 4; ++j)
            ST[sb + (tr * 4 + i) * 64 + tc + 16 * j] = f2b(st[i][j]);
    if (tid == 0) CDb[(((size_t)dir * B_ + b) * NH_ + h) * NC_ + c] = expneg_(alast);
}

// ---------------------------------------------------------------------------
// K3: inter-chunk scan, in place (ST[c] becomes the state BEFORE chunk c).
// grid: (64, 2), block 256, 16 state elements per thread, carry in f32.
// ---------------------------------------------------------------------------
__global__ __launch_bounds__(256) void k_scan(bf16* __restrict__ ST, const float* __restrict__ CDb)
{
    const int tid = threadIdx.x;
    const int dir = blockIdx.y;
    const int b = blockIdx.x >> 2, h = blockIdx.x & 3;
    const size_t cdbase = (((size_t)dir * B_ + b) * NH_ + h) * NC_;
    float carry[16];
#pragma unroll
    for (int q = 0; q < 16; ++q) carry[q] = 0.f;
    for (int c = 0; c < NC_; ++c) {
        const float cd = CDb[cdbase + c];
        size_t base = ((((size_t)dir * B_ + b) * NC_ + c) * NH_ + h) * 4096 + tid;
#pragma unroll
        for (int q = 0; q < 16; ++q) {
            float v = b2f(ST[base + q * 256]);
            ST[base + q * 256] = f2b(carry[q]);
            carry[q] = carry[q] * cd + v;
        }
    }
}

// ---------------------------------------------------------------------------
// K4: Y += exp(Acs[l]) * C @ prev^T  (off-diagonal / inter-chunk term).
// grid: (32, 16, 2), block 256, loops over the 4 heads.
// ---------------------------------------------------------------------------
__global__ __launch_bounds__(256) void k_offdiag(
    const bf16* __restrict__ XBC, const float* __restrict__ DTV,
    const float* __restrict__ AlF, const float* __restrict__ AlB,
    const bf16* __restrict__ ST, bf16* __restrict__ Y)
{
    const int tid = threadIdx.x;
    const int c = blockIdx.x, b = blockIdx.y, dir = blockIdx.z;
    const float* Al = dir ? AlB : AlF;
    const int t0 = b * L_ + c * 64;
    __shared__ float Cs[64][65];
    __shared__ float Ps[64][65];
    __shared__ float dts[64];
    __shared__ float Acs[64];
    for (int i = tid; i < 4096; i += 256) {
        int l = i >> 6, n = i & 63;
        Cs[l][n] = b2f(XBC[((size_t)dir * T_ + t0 + l) * DXBC_ + 320 + n]);
    }
    const int tr = tid >> 4, tc = tid & 15;
    for (int h = 0; h < NH_; ++h) {
        __syncthreads();
        if (tid < 64) dts[tid] = DTV[((size_t)dir * T_ + t0 + tid) * NH_ + h];
        __syncthreads();
        if (tid == 0) {
            float A = -expf(Al[h]);
            float r = 0.f;
            for (int l = 0; l < 64; ++l) { r += dts[l] * A; Acs[l] = r; }
        }
        size_t sb = ((((size_t)dir * B_ + b) * NC_ + c) * NH_ + h) * 4096;
        for (int i = tid; i < 4096; i += 256) Ps[i >> 6][i & 63] = b2f(ST[sb + i]);
        __syncthreads();
        float acc[4][4] = {{0.f, 0.f, 0.f, 0.f}, {0.f, 0.f, 0.f, 0.f},
                           {0.f, 0.f, 0.f, 0.f}, {0.f, 0.f, 0.f, 0.f}};
        for (int n = 0; n < 64; ++n) {
            float cv[4], pv[4];
#pragma unroll
            for (int i = 0; i < 4; ++i) cv[i] = Cs[tr * 4 + i][n];
#pragma unroll
            for (int j = 0; j < 4; ++j) pv[j] = Ps[tc + 16 * j][n];
#pragma unroll
            for (int i = 0; i < 4; ++i)
#pragma unroll
                for (int j = 0; j < 4; ++j) acc[i][j] += cv[i] * pv[j];
        }
#pragma unroll
        for (int i = 0; i < 4; ++i)
#pragma unroll
            for (int j = 0; j < 4; ++j) {
                int l = tr * 4 + i, p = tc + 16 * j;
                size_t gi = ((size_t)dir * T_ + t0 + l) * DI_ + h * HD_ + p;
                Y[gi] = f2b(b2f(Y[gi]) + acc[i][j] * expneg_(Acs[l]));
            }
        __syncthreads();   // Acs reads done before next h rewrites it
    }
}

// ---------------------------------------------------------------------------
// K5: y = Y * silu(z); RMSNorm over 256 channels; in place over Y.
// grid: (2048, 16, 2), block 256 (one token per block).
// ---------------------------------------------------------------------------
__global__ __launch_bounds__(256) void k_gate(
    const bf16* __restrict__ Z, const float* __restrict__ nwF, const float* __restrict__ nwB,
    bf16* __restrict__ Y)
{
    const int tid = threadIdx.x;
    const int t = blockIdx.y * L_ + blockIdx.x;
    const int dir = blockIdx.z;
    const float* nw = dir ? nwB : nwF;
    size_t gi = ((size_t)dir * T_ + t) * DI_ + tid;
    float v = b2f(Y[gi]);
    float zv = b2f(Z[gi]);
    v *= zv * sigmoidf_(zv);
    __shared__ float red[256];
    red[tid] = v * v;
    __syncthreads();
    for (int s = 128; s > 0; s >>= 1) {
        if (tid < s) red[tid] += red[tid + s];
        __syncthreads();
    }
    float r = rsqrtf(red[0] * (1.f / 256.f) + 1e-5f);
    Y[gi] = f2b(v * r * nw[tid]);
}

// ---------------------------------------------------------------------------
// K6: out[t] = y_f[t] @ Wo_f^T + y_b[flip(t)] @ Wo_b^T. grid 512, block 256.
// ---------------------------------------------------------------------------
__global__ __launch_bounds__(256) void k_outproj(
    const bf16* __restrict__ Y, const float* __restrict__ WoF, const float* __restrict__ WoB,
    float* __restrict__ out)
{
    const int tid = threadIdx.x;
    const int t0 = blockIdx.x * 64;
    const int batch = t0 >> 11;
    const int l0 = t0 & (L_ - 1);
    __shared__ float ys[64][65];
    __shared__ float wsm[128][65];
    const int tr = tid >> 4, tc = tid & 15;
    float acc[4][8];
#pragma unroll
    for (int i = 0; i < 4; ++i)
#pragma unroll
        for (int j = 0; j < 8; ++j) acc[i][j] = 0.f;

    for (int dir = 0; dir < 2; ++dir) {
        const float* Wo = dir ? WoB : WoF;
        for (int kt = 0; kt < 4; ++kt) {
            const int k0 = kt * 64;
            __syncthreads();
            for (int i = tid; i < 64 * 64; i += 256) {
                int r = i >> 6, kk = i & 63;
                int tsrc = dir ? (batch * L_ + (L_ - 1 - (l0 + r))) : (t0 + r);
                ys[r][kk] = b2f(Y[((size_t)dir * T_ + tsrc) * DI_ + k0 + kk]);
            }
            for (int i = tid; i < 128 * 64; i += 256) {
                int m = i >> 6, kk = i & 63;
                wsm[m][kk] = Wo[(size_t)m * DI_ + k0 + kk];
            }
            __syncthreads();
            for (int kk = 0; kk < 64; ++kk) {
                float av[4], bv[8];
#pragma unroll
                for (int i = 0; i < 4; ++i) av[i] = ys[tr * 4 + i][kk];
#pragma unroll
                for (int j = 0; j < 8; ++j) bv[j] = wsm[tc + 16 * j][kk];
#pragma unroll
                for (int i = 0; i < 4; ++i)
#pragma unroll
                    for (int j = 0; j < 8; ++j) acc[i][j] += av[i] * bv[j];
            }
        }
    }
#pragma unroll
    for (int i = 0; i < 4; ++i)
#pragma unroll
        for (int j = 0; j < 8; ++j)
            out[((size_t)(t0 + tr * 4 + i)) * DM_ + tc + 16 * j] = acc[i][j];
}

// ---------------------------------------------------------------------------
extern "C" void kernel_launch(void* const* d_in, const int* in_sizes, int n_in,
                              void* d_out, int out_size, void* d_ws, size_t ws_size,
                              hipStream_t stream)
{
    const float* x    = (const float*)d_in[0];
    const float* WiF  = (const float*)d_in[1];
    const float* cwF  = (const float*)d_in[2];
    const float* cbF  = (const float*)d_in[3];
    const float* dtbF = (const float*)d_in[4];
    const float* AlF  = (const float*)d_in[5];
    const float* DpF  = (const float*)d_in[6];
    const float* nwF  = (const float*)d_in[7];
    const float* WoF  = (const float*)d_in[8];
    const float* WiB  = (const float*)d_in[9];
    const float* cwB  = (const float*)d_in[10];
    const float* cbB  = (const float*)d_in[11];
    const float* dtbB = (const float*)d_in[12];
    const float* AlB  = (const float*)d_in[13];
    const float* DpB  = (const float*)d_in[14];
    const float* nwB  = (const float*)d_in[15];
    const float* WoB  = (const float*)d_in[16];

    // workspace layout: bf16 intermediates + f32 dt/decays (~152 MB)
    const size_t nZ   = (size_t)2 * T_ * DI_;       // bf16
    const size_t nXBC = (size_t)2 * T_ * DXBC_;     // bf16
    const size_t nY   = (size_t)2 * T_ * DI_;       // bf16
    const size_t nST  = (size_t)2 * B_ * NC_ * NH_ * HD_ * DS_;  // bf16
    const size_t nDTV = (size_t)2 * T_ * NH_;       // f32
    const size_t nCD  = (size_t)2 * B_ * NH_ * NC_; // f32
    const size_t need = (nZ + nXBC + nY + nST) * sizeof(bf16)
                      + (nDTV + nCD) * sizeof(float);
    if (ws_size < need) return;  // fail loudly (output stays poisoned)

    char* p = (char*)d_ws;
    bf16* Z    = (bf16*)p;            p += nZ * sizeof(bf16);
    bf16* XBC  = (bf16*)p;            p += nXBC * sizeof(bf16);
    bf16* Yb   = (bf16*)p;            p += nY * sizeof(bf16);
    bf16* ST   = (bf16*)p;            p += nST * sizeof(bf16);
    float* DTV = (float*)p;           p += nDTV * sizeof(float);
    float* CDb = (float*)p;

    k_inproj<<<dim3(512, 11, 2), 256, 0, stream>>>(x, WiF, WiB, cwF, cbF, cwB, cbB,
                                                   dtbF, dtbB, Z, XBC, DTV);
    k_chunkdiag<<<dim3(NC_, B_ * NH_, 2), 256, 0, stream>>>(XBC, DTV, AlF, AlB, DpF, DpB,
                                                            Yb, ST, CDb);
    k_scan<<<dim3(B_ * NH_, 2), 256, 0, stream>>>(ST, CDb);
    k_offdiag<<<dim3(NC_, B_, 2), 256, 0, stream>>>(XBC, DTV, AlF, AlB, ST, Yb);
    k_gate<<<dim3(L_, B_, 2), 256, 0, stream>>>(Z, nwF, nwB, Yb);
    k_outproj<<<dim3(512), 256, 0, stream>>>(Yb, WoF, WoB, (float*)d_out);
}

// Round 4
// 523.711 us; speedup vs baseline: 2.7353x; 2.7353x over previous
//
#include <hip/hip_runtime.h>
#include <hip/hip_bf16.h>
#include <cmath>

#define B_    16
#define L_    2048
#define T_    32768   // B_*L_
#define DM_   128
#define DI_   256
#define DXBC_ 384
#define DS_   64
#define HD_   64
#define NH_   4
#define NC_   32      // chunks per sequence (L_/64)

typedef __hip_bfloat16 bf16;
typedef __attribute__((ext_vector_type(8))) short short8;
typedef __attribute__((ext_vector_type(4))) float f32x4;

__device__ __forceinline__ float b2f(bf16 v) { return __bfloat162float(v); }
__device__ __forceinline__ bf16  f2b(float f) { return __float2bfloat16(f); }
__device__ __forceinline__ short f2bs(float f) { bf16 h = __float2bfloat16(f); return *reinterpret_cast<short*>(&h); }
__device__ __forceinline__ float bs2f(short s) { bf16 h = *reinterpret_cast<bf16*>(&s); return __bfloat162float(h); }
__device__ __forceinline__ float sigmoidf_(float x) { return 1.f / (1.f + expf(-x)); }
__device__ __forceinline__ float softplusf_(float x) { return (x > 20.f) ? x : log1pf(expf(x)); }
// decay exp: argument is mathematically <= 0; clamp kills any speculative inf
__device__ __forceinline__ float expneg_(float x) { return expf(fminf(x, 0.f)); }

struct __align__(8) S4 { short a, b, c, d; };

// ---------------------------------------------------------------------------
// K1 (MFMA): in_proj GEMM (x @ Wi^T, bf16 MFMA) fused with causal conv1d
// (+bias, SiLU) for xBC columns; dt (4 cols) via VALU; z via LDS round-trip
// for coalesced stores. grid: (512 token-tiles, 2 dirs), block 256 (4 waves).
// A-tile = 80 rows: tokens l0-16..l0+63 (rows 13..15 are the conv halo).
// ---------------------------------------------------------------------------
__global__ __launch_bounds__(256) void k_inproj_mfma(
    const float* __restrict__ x,
    const float* __restrict__ WiF, const float* __restrict__ WiB,
    const float* __restrict__ cwF, const float* __restrict__ cbF,
    const float* __restrict__ cwB, const float* __restrict__ cbB,
    const float* __restrict__ dtbF, const float* __restrict__ dtbB,
    bf16* __restrict__ Z, bf16* __restrict__ XBC, float* __restrict__ DTV)
{
    const int tid  = threadIdx.x;
    const int wave = tid >> 6, lane = tid & 63;
    const int ln15 = lane & 15, q = lane >> 4;
    const int dir  = blockIdx.y;
    const float* Wi = dir ? WiB : WiF;
    const int t0 = blockIdx.x * 64;
    const int batch = t0 >> 11, l0 = t0 & (L_ - 1);

    // A-tile: 80 rows x 128 k, stride 136 shorts (272B: 16B-aligned rows,
    // bank step 4 dwords -> only 2-way aliasing on ds_read_b128 = free).
    __shared__ __align__(16) short xs[80][136];
    __shared__ __align__(16) char  smem[80 * 66 * 4];   // union: ws (17.4KB) / raws (21.1KB)
    short (*ws)[136]  = (short(*)[136])smem;
    float (*raws)[66] = (float(*)[66])smem;

    // ---- stage A-tile (f32 -> bf16) ----
    for (int i = tid; i < 80 * 32; i += 256) {
        int r = i >> 5, c4 = (i & 31) * 4;
        int l = l0 - 16 + r;
        float4 v = make_float4(0.f, 0.f, 0.f, 0.f);
        if (l >= 0) {
            int sl = dir ? (L_ - 1 - l) : l;
            v = *(const float4*)&x[((size_t)batch * L_ + sl) * DM_ + c4];
        }
        S4 s; s.a = f2bs(v.x); s.b = f2bs(v.y); s.c = f2bs(v.z); s.d = f2bs(v.w);
        *(S4*)&xs[r][c4] = s;
    }
    __syncthreads();

    for (int nt = 0; nt < 10; ++nt) {
        const int c0 = nt * 64;
        __syncthreads();   // prior epilogue's raws reads complete
        // ---- stage Wi tile (64 cols x 128 k) ----
        for (int i = tid; i < 64 * 32; i += 256) {
            int r = i >> 5, c4 = (i & 31) * 4;
            float4 v = *(const float4*)&Wi[(size_t)(c0 + r) * DM_ + c4];
            S4 s; s.a = f2bs(v.x); s.b = f2bs(v.y); s.c = f2bs(v.z); s.d = f2bs(v.w);
            *(S4*)&ws[r][c4] = s;
        }
        __syncthreads();

        f32x4 acc[5];
#pragma unroll
        for (int mt = 0; mt < 5; ++mt) acc[mt] = (f32x4){0.f, 0.f, 0.f, 0.f};
#pragma unroll
        for (int ks = 0; ks < 4; ++ks) {
            short8 bfr = *(const short8*)&ws[16 * wave + ln15][ks * 32 + q * 8];
#pragma unroll
            for (int mt = 0; mt < 5; ++mt) {
                short8 afr = *(const short8*)&xs[16 * mt + ln15][ks * 32 + q * 8];
                acc[mt] = __builtin_amdgcn_mfma_f32_16x16x32_bf16(afr, bfr, acc[mt], 0, 0, 0);
            }
        }
        __syncthreads();   // all ws reads done; raws may overwrite
#pragma unroll
        for (int mt = 0; mt < 5; ++mt)
#pragma unroll
            for (int rg = 0; rg < 4; ++rg)
                raws[16 * mt + 4 * q + rg][16 * wave + ln15] = acc[mt][rg];
        __syncthreads();

        if (nt < 4) {
            // z columns: coalesced bf16 stores from raws
            for (int i = tid; i < 4096; i += 256) {
                int row = i >> 6, c = i & 63;
                Z[((size_t)dir * T_ + t0 + row) * DI_ + c0 + c] = f2b(raws[16 + row][c]);
            }
        } else {
            // xBC columns: causal conv (D_CONV=4) + SiLU, coalesced stores
            const float* cw = dir ? cwB : cwF;
            const float* cb = dir ? cbB : cbF;
            for (int i = tid; i < 4096; i += 256) {
                int row = i >> 6, c = i & 63;
                int ch = c0 - 256 + c;
                float s = cb[ch];
#pragma unroll
                for (int k = 0; k < 4; ++k) s += raws[13 + row + k][c] * cw[ch * 4 + k];
                s = s * sigmoidf_(s);
                XBC[((size_t)dir * T_ + t0 + row) * DXBC_ + ch] = f2b(s);
            }
        }
    }

    // ---- dt columns (4): VALU dot from LDS A-tile ----
    {
        const float* dtb = dir ? dtbB : dtbF;
        int row = tid >> 2, hc = tid & 3;
        const float* wrow = Wi + (size_t)(640 + hc) * DM_;
        float a = 0.f;
#pragma unroll 8
        for (int k = 0; k < 128; ++k) a += bs2f(xs[16 + row][k]) * wrow[k];
        DTV[((size_t)dir * T_ + t0 + row) * NH_ + hc] = softplusf_(a + dtb[hc]);
    }
}

// ---------------------------------------------------------------------------
// K2: per (chunk, b, h, dir): diag block Yd = (L ∘ C B^T) Xdt + D*x, and
// chunk states st[p][n] = sum_l dec[l] Xdt[l][p] B[l][n].
// grid: (32, 64, 2), block 256.
// ---------------------------------------------------------------------------
__global__ __launch_bounds__(256) void k_chunkdiag(
    const bf16* __restrict__ XBC, const float* __restrict__ DTV,
    const float* __restrict__ AlF, const float* __restrict__ AlB,
    const float* __restrict__ DpF, const float* __restrict__ DpB,
    bf16* __restrict__ Y, bf16* __restrict__ ST, float* __restrict__ CDb)
{
    const int tid = threadIdx.x;
    const int c = blockIdx.x;
    const int b = blockIdx.y >> 2;
    const int h = blockIdx.y & 3;
    const int dir = blockIdx.z;
    const float Ah = -expf((dir ? AlB : AlF)[h]);
    const float Dh = (dir ? DpB : DpF)[h];
    const int t0 = b * L_ + c * 64;

    __shared__ float Bs[64][65];
    __shared__ float Cs[64][65];   // reused as M after G is computed
    __shared__ float Xs[64][65];   // Xdt, later dec-scaled in place
    __shared__ float dts[64];
    __shared__ float Acs[64];

    if (tid < 64) dts[tid] = DTV[((size_t)dir * T_ + t0 + tid) * NH_ + h];
    __syncthreads();
    if (tid == 0) {
        float r = 0.f;
        for (int l = 0; l < 64; ++l) { r += dts[l] * Ah; Acs[l] = r; }
    }
    for (int i = tid; i < 4096; i += 256) {
        int l = i >> 6, n = i & 63;
        size_t base = ((size_t)dir * T_ + t0 + l) * DXBC_;
        Bs[l][n] = b2f(XBC[base + 256 + n]);
        Cs[l][n] = b2f(XBC[base + 320 + n]);
        Xs[l][n] = b2f(XBC[base + h * HD_ + n]) * dts[l];
    }
    __syncthreads();

    const int tr = tid >> 4, tc = tid & 15;
    // G = C B^T
    float g[4][4] = {{0.f, 0.f, 0.f, 0.f}, {0.f, 0.f, 0.f, 0.f},
                     {0.f, 0.f, 0.f, 0.f}, {0.f, 0.f, 0.f, 0.f}};
    for (int n = 0; n < 64; ++n) {
        float cv[4], bv[4];
#pragma unroll
        for (int i = 0; i < 4; ++i) cv[i] = Cs[tr * 4 + i][n];
#pragma unroll
        for (int j = 0; j < 4; ++j) bv[j] = Bs[tc + 16 * j][n];
#pragma unroll
        for (int i = 0; i < 4; ++i)
#pragma unroll
            for (int j = 0; j < 4; ++j) g[i][j] += cv[i] * bv[j];
    }
    __syncthreads();   // all G reads of Cs done; reuse Cs as M
#pragma unroll
    for (int i = 0; i < 4; ++i)
#pragma unroll
        for (int j = 0; j < 4; ++j) {
            int l = tr * 4 + i, s = tc + 16 * j;
            Cs[l][s] = (s <= l) ? g[i][j] * expneg_(Acs[l] - Acs[s]) : 0.f;
        }
    __syncthreads();
    // Yd = M @ Xdt
    float acc[4][4] = {{0.f, 0.f, 0.f, 0.f}, {0.f, 0.f, 0.f, 0.f},
                       {0.f, 0.f, 0.f, 0.f}, {0.f, 0.f, 0.f, 0.f}};
    for (int s = 0; s < 64; ++s) {
        float mv[4], xv[4];
#pragma unroll
        for (int i = 0; i < 4; ++i) mv[i] = Cs[tr * 4 + i][s];
#pragma unroll
        for (int j = 0; j < 4; ++j) xv[j] = Xs[s][tc + 16 * j];
#pragma unroll
        for (int i = 0; i < 4; ++i)
#pragma unroll
            for (int j = 0; j < 4; ++j) acc[i][j] += mv[i] * xv[j];
    }
#pragma unroll
    for (int i = 0; i < 4; ++i)
#pragma unroll
        for (int j = 0; j < 4; ++j) {
            int l = tr * 4 + i, p = tc + 16 * j;
            size_t tI = (size_t)dir * T_ + t0 + l;
            float xraw = b2f(XBC[tI * DXBC_ + h * HD_ + p]);
            Y[tI * DI_ + h * HD_ + p] = f2b(acc[i][j] + Dh * xraw);
        }
    __syncthreads();
    const float alast = Acs[63];
    for (int i = tid; i < 4096; i += 256) {
        int l = i >> 6;
        Xs[l][i & 63] *= expneg_(alast - Acs[l]);
    }
    __syncthreads();
    // st[p][n] = sum_l XdtDec[l][p] * B[l][n]
    float st[4][4] = {{0.f, 0.f, 0.f, 0.f}, {0.f, 0.f, 0.f, 0.f},
                      {0.f, 0.f, 0.f, 0.f}, {0.f, 0.f, 0.f, 0.f}};
    for (int l = 0; l < 64; ++l) {
        float xv[4], bv[4];
#pragma unroll
        for (int i = 0; i < 4; ++i) xv[i] = Xs[l][tr * 4 + i];
#pragma unroll
        for (int j = 0; j < 4; ++j) bv[j] = Bs[l][tc + 16 * j];
#pragma unroll
        for (int i = 0; i < 4; ++i)
#pragma unroll
            for (int j = 0; j < 4; ++j) st[i][j] += xv[i] * bv[j];
    }
    size_t sb = ((((size_t)dir * B_ + b) * NC_ + c) * NH_ + h) * 4096;
#pragma unroll
    for (int i = 0; i < 4; ++i)
#pragma unroll
        for (int j = 0; j < 4; ++j)
            ST[sb + (tr * 4 + i) * 64 + tc + 16 * j] = f2b(st[i][j]);
    if (tid == 0) CDb[(((size_t)dir * B_ + b) * NH_ + h) * NC_ + c] = expneg_(alast);
}

// ---------------------------------------------------------------------------
// K3: inter-chunk scan, in place (ST[c] becomes the state BEFORE chunk c).
// grid: (64, 2), block 256, 16 state elements per thread, carry in f32.
// ---------------------------------------------------------------------------
__global__ __launch_bounds__(256) void k_scan(bf16* __restrict__ ST, const float* __restrict__ CDb)
{
    const int tid = threadIdx.x;
    const int dir = blockIdx.y;
    const int b = blockIdx.x >> 2, h = blockIdx.x & 3;
    const size_t cdbase = (((size_t)dir * B_ + b) * NH_ + h) * NC_;
    float carry[16];
#pragma unroll
    for (int q = 0; q < 16; ++q) carry[q] = 0.f;
    for (int c = 0; c < NC_; ++c) {
        const float cd = CDb[cdbase + c];
        size_t base = ((((size_t)dir * B_ + b) * NC_ + c) * NH_ + h) * 4096 + tid;
#pragma unroll
        for (int q = 0; q < 16; ++q) {
            float v = b2f(ST[base + q * 256]);
            ST[base + q * 256] = f2b(carry[q]);
            carry[q] = carry[q] * cd + v;
        }
    }
}

// ---------------------------------------------------------------------------
// K4: Y += exp(Acs[l]) * C @ prev^T  (off-diagonal / inter-chunk term).
// grid: (32, 16, 2), block 256, loops over the 4 heads.
// ---------------------------------------------------------------------------
__global__ __launch_bounds__(256) void k_offdiag(
    const bf16* __restrict__ XBC, const float* __restrict__ DTV,
    const float* __restrict__ AlF, const float* __restrict__ AlB,
    const bf16* __restrict__ ST, bf16* __restrict__ Y)
{
    const int tid = threadIdx.x;
    const int c = blockIdx.x, b = blockIdx.y, dir = blockIdx.z;
    const float* Al = dir ? AlB : AlF;
    const int t0 = b * L_ + c * 64;
    __shared__ float Cs[64][65];
    __shared__ float Ps[64][65];
    __shared__ float dts[64];
    __shared__ float Acs[64];
    for (int i = tid; i < 4096; i += 256) {
        int l = i >> 6, n = i & 63;
        Cs[l][n] = b2f(XBC[((size_t)dir * T_ + t0 + l) * DXBC_ + 320 + n]);
    }
    const int tr = tid >> 4, tc = tid & 15;
    for (int h = 0; h < NH_; ++h) {
        __syncthreads();
        if (tid < 64) dts[tid] = DTV[((size_t)dir * T_ + t0 + tid) * NH_ + h];
        __syncthreads();
        if (tid == 0) {
            float A = -expf(Al[h]);
            float r = 0.f;
            for (int l = 0; l < 64; ++l) { r += dts[l] * A; Acs[l] = r; }
        }
        size_t sb = ((((size_t)dir * B_ + b) * NC_ + c) * NH_ + h) * 4096;
        for (int i = tid; i < 4096; i += 256) Ps[i >> 6][i & 63] = b2f(ST[sb + i]);
        __syncthreads();
        float acc[4][4] = {{0.f, 0.f, 0.f, 0.f}, {0.f, 0.f, 0.f, 0.f},
                           {0.f, 0.f, 0.f, 0.f}, {0.f, 0.f, 0.f, 0.f}};
        for (int n = 0; n < 64; ++n) {
            float cv[4], pv[4];
#pragma unroll
            for (int i = 0; i < 4; ++i) cv[i] = Cs[tr * 4 + i][n];
#pragma unroll
            for (int j = 0; j < 4; ++j) pv[j] = Ps[tc + 16 * j][n];
#pragma unroll
            for (int i = 0; i < 4; ++i)
#pragma unroll
                for (int j = 0; j < 4; ++j) acc[i][j] += cv[i] * pv[j];
        }
#pragma unroll
        for (int i = 0; i < 4; ++i)
#pragma unroll
            for (int j = 0; j < 4; ++j) {
                int l = tr * 4 + i, p = tc + 16 * j;
                size_t gi = ((size_t)dir * T_ + t0 + l) * DI_ + h * HD_ + p;
                Y[gi] = f2b(b2f(Y[gi]) + acc[i][j] * expneg_(Acs[l]));
            }
        __syncthreads();   // Acs reads done before next h rewrites it
    }
}

// ---------------------------------------------------------------------------
// K5: y = Y * silu(z); RMSNorm over 256 channels; in place over Y.
// grid: (2048, 16, 2), block 256 (one token per block).
// ---------------------------------------------------------------------------
__global__ __launch_bounds__(256) void k_gate(
    const bf16* __restrict__ Z, const float* __restrict__ nwF, const float* __restrict__ nwB,
    bf16* __restrict__ Y)
{
    const int tid = threadIdx.x;
    const int t = blockIdx.y * L_ + blockIdx.x;
    const int dir = blockIdx.z;
    const float* nw = dir ? nwB : nwF;
    size_t gi = ((size_t)dir * T_ + t) * DI_ + tid;
    float v = b2f(Y[gi]);
    float zv = b2f(Z[gi]);
    v *= zv * sigmoidf_(zv);
    __shared__ float red[256];
    red[tid] = v * v;
    __syncthreads();
    for (int s = 128; s > 0; s >>= 1) {
        if (tid < s) red[tid] += red[tid + s];
        __syncthreads();
    }
    float r = rsqrtf(red[0] * (1.f / 256.f) + 1e-5f);
    Y[gi] = f2b(v * r * nw[tid]);
}

// ---------------------------------------------------------------------------
// K6: out[t] = y_f[t] @ Wo_f^T + y_b[flip(t)] @ Wo_b^T. grid 512, block 256.
// ---------------------------------------------------------------------------
__global__ __launch_bounds__(256) void k_outproj(
    const bf16* __restrict__ Y, const float* __restrict__ WoF, const float* __restrict__ WoB,
    float* __restrict__ out)
{
    const int tid = threadIdx.x;
    const int t0 = blockIdx.x * 64;
    const int batch = t0 >> 11;
    const int l0 = t0 & (L_ - 1);
    __shared__ float ys[64][65];
    __shared__ float wsm[128][65];
    const int tr = tid >> 4, tc = tid & 15;
    float acc[4][8];
#pragma unroll
    for (int i = 0; i < 4; ++i)
#pragma unroll
        for (int j = 0; j < 8; ++j) acc[i][j] = 0.f;

    for (int dir = 0; dir < 2; ++dir) {
        const float* Wo = dir ? WoB : WoF;
        for (int kt = 0; kt < 4; ++kt) {
            const int k0 = kt * 64;
            __syncthreads();
            for (int i = tid; i < 64 * 64; i += 256) {
                int r = i >> 6, kk = i & 63;
                int tsrc = dir ? (batch * L_ + (L_ - 1 - (l0 + r))) : (t0 + r);
                ys[r][kk] = b2f(Y[((size_t)dir * T_ + tsrc) * DI_ + k0 + kk]);
            }
            for (int i = tid; i < 128 * 64; i += 256) {
                int m = i >> 6, kk = i & 63;
                wsm[m][kk] = Wo[(size_t)m * DI_ + k0 + kk];
            }
            __syncthreads();
            for (int kk = 0; kk < 64; ++kk) {
                float av[4], bv[8];
#pragma unroll
                for (int i = 0; i < 4; ++i) av[i] = ys[tr * 4 + i][kk];
#pragma unroll
                for (int j = 0; j < 8; ++j) bv[j] = wsm[tc + 16 * j][kk];
#pragma unroll
                for (int i = 0; i < 4; ++i)
#pragma unroll
                    for (int j = 0; j < 8; ++j) acc[i][j] += av[i] * bv[j];
            }
        }
    }
#pragma unroll
    for (int i = 0; i < 4; ++i)
#pragma unroll
        for (int j = 0; j < 8; ++j)
            out[((size_t)(t0 + tr * 4 + i)) * DM_ + tc + 16 * j] = acc[i][j];
}

// ---------------------------------------------------------------------------
extern "C" void kernel_launch(void* const* d_in, const int* in_sizes, int n_in,
                              void* d_out, int out_size, void* d_ws, size_t ws_size,
                              hipStream_t stream)
{
    const float* x    = (const float*)d_in[0];
    const float* WiF  = (const float*)d_in[1];
    const float* cwF  = (const float*)d_in[2];
    const float* cbF  = (const float*)d_in[3];
    const float* dtbF = (const float*)d_in[4];
    const float* AlF  = (const float*)d_in[5];
    const float* DpF  = (const float*)d_in[6];
    const float* nwF  = (const float*)d_in[7];
    const float* WoF  = (const float*)d_in[8];
    const float* WiB  = (const float*)d_in[9];
    const float* cwB  = (const float*)d_in[10];
    const float* cbB  = (const float*)d_in[11];
    const float* dtbB = (const float*)d_in[12];
    const float* AlB  = (const float*)d_in[13];
    const float* DpB  = (const float*)d_in[14];
    const float* nwB  = (const float*)d_in[15];
    const float* WoB  = (const float*)d_in[16];

    // workspace layout: bf16 intermediates + f32 dt/decays (~152 MB)
    const size_t nZ   = (size_t)2 * T_ * DI_;       // bf16
    const size_t nXBC = (size_t)2 * T_ * DXBC_;     // bf16
    const size_t nY   = (size_t)2 * T_ * DI_;       // bf16
    const size_t nST  = (size_t)2 * B_ * NC_ * NH_ * HD_ * DS_;  // bf16
    const size_t nDTV = (size_t)2 * T_ * NH_;       // f32
    const size_t nCD  = (size_t)2 * B_ * NH_ * NC_; // f32
    const size_t need = (nZ + nXBC + nY + nST) * sizeof(bf16)
                      + (nDTV + nCD) * sizeof(float);
    if (ws_size < need) return;  // fail loudly (output stays poisoned)

    char* p = (char*)d_ws;
    bf16* Z    = (bf16*)p;            p += nZ * sizeof(bf16);
    bf16* XBC  = (bf16*)p;            p += nXBC * sizeof(bf16);
    bf16* Yb   = (bf16*)p;            p += nY * sizeof(bf16);
    bf16* ST   = (bf16*)p;            p += nST * sizeof(bf16);
    float* DTV = (float*)p;           p += nDTV * sizeof(float);
    float* CDb = (float*)p;

    k_inproj_mfma<<<dim3(512, 2), 256, 0, stream>>>(x, WiF, WiB, cwF, cbF, cwB, cbB,
                                                    dtbF, dtbB, Z, XBC, DTV);
    k_chunkdiag<<<dim3(NC_, B_ * NH_, 2), 256, 0, stream>>>(XBC, DTV, AlF, AlB, DpF, DpB,
                                                            Yb, ST, CDb);
    k_scan<<<dim3(B_ * NH_, 2), 256, 0, stream>>>(ST, CDb);
    k_offdiag<<<dim3(NC_, B_, 2), 256, 0, stream>>>(XBC, DTV, AlF, AlB, ST, Yb);
    k_gate<<<dim3(L_, B_, 2), 256, 0, stream>>>(Z, nwF, nwB, Yb);
    k_outproj<<<dim3(512), 256, 0, stream>>>(Yb, WoF, WoB, (float*)d_out);
}

// Round 5
// 361.596 us; speedup vs baseline: 3.9617x; 1.4483x over previous
//
#include <hip/hip_runtime.h>
#include <hip/hip_bf16.h>
#include <cmath>

#define B_    16
#define L_    2048
#define T_    32768   // B_*L_
#define DM_   128
#define DI_   256
#define DXBC_ 384
#define DS_   64
#define HD_   64
#define NH_   4
#define NC_   32      // chunks per sequence (L_/64)

typedef __hip_bfloat16 bf16;
typedef __attribute__((ext_vector_type(8))) short short8;
typedef __attribute__((ext_vector_type(4))) float f32x4;

__device__ __forceinline__ float b2f(bf16 v) { return __bfloat162float(v); }
__device__ __forceinline__ bf16  f2b(float f) { return __float2bfloat16(f); }
__device__ __forceinline__ short f2bs(float f) { bf16 h = __float2bfloat16(f); return *reinterpret_cast<short*>(&h); }
__device__ __forceinline__ float bs2f(short s) { bf16 h = *reinterpret_cast<bf16*>(&s); return __bfloat162float(h); }
__device__ __forceinline__ float sigmoidf_(float x) { return 1.f / (1.f + expf(-x)); }
__device__ __forceinline__ float softplusf_(float x) { return (x > 20.f) ? x : log1pf(expf(x)); }
// decay exp: argument is mathematically <= 0; clamp kills any speculative inf
__device__ __forceinline__ float expneg_(float x) { return expf(fminf(x, 0.f)); }

struct __align__(8) S4 { short a, b, c, d; };

// ---------------------------------------------------------------------------
// K1 (MFMA): in_proj GEMM (x @ Wi^T, bf16 MFMA) fused with causal conv1d
// (+bias, SiLU) for xBC columns; dt (4 cols) via VALU; z via LDS round-trip
// for coalesced stores. grid: (512 token-tiles, 2 dirs), block 256 (4 waves).
// A-tile = 80 rows: tokens l0-16..l0+63 (rows 13..15 are the conv halo).
// ---------------------------------------------------------------------------
__global__ __launch_bounds__(256) void k_inproj_mfma(
    const float* __restrict__ x,
    const float* __restrict__ WiF, const float* __restrict__ WiB,
    const float* __restrict__ cwF, const float* __restrict__ cbF,
    const float* __restrict__ cwB, const float* __restrict__ cbB,
    const float* __restrict__ dtbF, const float* __restrict__ dtbB,
    bf16* __restrict__ Z, bf16* __restrict__ XBC, float* __restrict__ DTV)
{
    const int tid  = threadIdx.x;
    const int wave = tid >> 6, lane = tid & 63;
    const int ln15 = lane & 15, q = lane >> 4;
    const int dir  = blockIdx.y;
    const float* Wi = dir ? WiB : WiF;
    const int t0 = blockIdx.x * 64;
    const int batch = t0 >> 11, l0 = t0 & (L_ - 1);

    __shared__ __align__(16) short xs[80][136];
    __shared__ __align__(16) char  smem[80 * 66 * 4];   // union: ws / raws
    short (*ws)[136]  = (short(*)[136])smem;
    float (*raws)[66] = (float(*)[66])smem;

    // ---- stage A-tile (f32 -> bf16) ----
    for (int i = tid; i < 80 * 32; i += 256) {
        int r = i >> 5, c4 = (i & 31) * 4;
        int l = l0 - 16 + r;
        float4 v = make_float4(0.f, 0.f, 0.f, 0.f);
        if (l >= 0) {
            int sl = dir ? (L_ - 1 - l) : l;
            v = *(const float4*)&x[((size_t)batch * L_ + sl) * DM_ + c4];
        }
        S4 s; s.a = f2bs(v.x); s.b = f2bs(v.y); s.c = f2bs(v.z); s.d = f2bs(v.w);
        *(S4*)&xs[r][c4] = s;
    }
    __syncthreads();

    for (int nt = 0; nt < 10; ++nt) {
        const int c0 = nt * 64;
        __syncthreads();   // prior epilogue's raws reads complete
        for (int i = tid; i < 64 * 32; i += 256) {
            int r = i >> 5, c4 = (i & 31) * 4;
            float4 v = *(const float4*)&Wi[(size_t)(c0 + r) * DM_ + c4];
            S4 s; s.a = f2bs(v.x); s.b = f2bs(v.y); s.c = f2bs(v.z); s.d = f2bs(v.w);
            *(S4*)&ws[r][c4] = s;
        }
        __syncthreads();

        f32x4 acc[5];
#pragma unroll
        for (int mt = 0; mt < 5; ++mt) acc[mt] = (f32x4){0.f, 0.f, 0.f, 0.f};
#pragma unroll
        for (int ks = 0; ks < 4; ++ks) {
            short8 bfr = *(const short8*)&ws[16 * wave + ln15][ks * 32 + q * 8];
#pragma unroll
            for (int mt = 0; mt < 5; ++mt) {
                short8 afr = *(const short8*)&xs[16 * mt + ln15][ks * 32 + q * 8];
                acc[mt] = __builtin_amdgcn_mfma_f32_16x16x32_bf16(afr, bfr, acc[mt], 0, 0, 0);
            }
        }
        __syncthreads();   // all ws reads done; raws may overwrite
#pragma unroll
        for (int mt = 0; mt < 5; ++mt)
#pragma unroll
            for (int rg = 0; rg < 4; ++rg)
                raws[16 * mt + 4 * q + rg][16 * wave + ln15] = acc[mt][rg];
        __syncthreads();

        if (nt < 4) {
            for (int i = tid; i < 4096; i += 256) {
                int row = i >> 6, c = i & 63;
                Z[((size_t)dir * T_ + t0 + row) * DI_ + c0 + c] = f2b(raws[16 + row][c]);
            }
        } else {
            const float* cw = dir ? cwB : cwF;
            const float* cb = dir ? cbB : cbF;
            for (int i = tid; i < 4096; i += 256) {
                int row = i >> 6, c = i & 63;
                int ch = c0 - 256 + c;
                float s = cb[ch];
#pragma unroll
                for (int k = 0; k < 4; ++k) s += raws[13 + row + k][c] * cw[ch * 4 + k];
                s = s * sigmoidf_(s);
                XBC[((size_t)dir * T_ + t0 + row) * DXBC_ + ch] = f2b(s);
            }
        }
    }

    // ---- dt columns (4): VALU dot from LDS A-tile ----
    {
        const float* dtb = dir ? dtbB : dtbF;
        int row = tid >> 2, hc = tid & 3;
        const float* wrow = Wi + (size_t)(640 + hc) * DM_;
        float a = 0.f;
#pragma unroll 8
        for (int k = 0; k < 128; ++k) a += bs2f(xs[16 + row][k]) * wrow[k];
        DTV[((size_t)dir * T_ + t0 + row) * NH_ + hc] = softplusf_(a + dtb[hc]);
    }
}

// ---------------------------------------------------------------------------
// K2 (MFMA): per (chunk, b, h, dir): G = C B^T, mask+decay, Yd = M Xdt + D*x,
// chunk states st = (Xdt*dec)^T B. grid: (32, 64, 2), block 256 (4 waves).
// ---------------------------------------------------------------------------
__global__ __launch_bounds__(256) void k_chunkdiag_mfma(
    const bf16* __restrict__ XBC, const float* __restrict__ DTV,
    const float* __restrict__ AlF, const float* __restrict__ AlB,
    const float* __restrict__ DpF, const float* __restrict__ DpB,
    bf16* __restrict__ Y, bf16* __restrict__ ST, float* __restrict__ CDb)
{
    const int tid = threadIdx.x;
    const int wave = tid >> 6, lane = tid & 63;
    const int ln15 = lane & 15, q = lane >> 4;
    const int c = blockIdx.x;
    const int b = blockIdx.y >> 2;
    const int h = blockIdx.y & 3;
    const int dir = blockIdx.z;
    const float Ah = -expf((dir ? AlB : AlF)[h]);
    const float Dh = (dir ? DpB : DpF)[h];
    const int t0 = b * L_ + c * 64;
    const size_t rowbase = (size_t)dir * T_ + t0;

    __shared__ __align__(16) short Bs[64][72];
    __shared__ __align__(16) short Cs[64][72];   // aliased as M after step 1
    __shared__ __align__(16) short Xt[64][72];   // Xdt transposed: Xt[p][l]
    __shared__ __align__(16) short Bt[64][72];   // Bt[n][l] = dec[l]*B[l][n]
    __shared__ float dts[64];
    __shared__ float Acs[64];
    __shared__ float decs[64];

    if (tid < 64) dts[tid] = DTV[(rowbase + tid) * NH_ + h];
    __syncthreads();   // B1: dts ready

    // stage B, C (row-major) and Xt (transposed, dt-scaled)
    for (int u = tid; u < 512; u += 256) {
        int r = u >> 3, g = u & 7;
        size_t base = (rowbase + r) * DXBC_;
        *(short8*)&Bs[r][g * 8] = *(const short8*)(XBC + base + 256 + g * 8);
        *(short8*)&Cs[r][g * 8] = *(const short8*)(XBC + base + 320 + g * 8);
    }
    for (int u = tid; u < 4096; u += 256) {
        int l = u >> 6, p = u & 63;
        Xt[p][l] = f2bs(b2f(XBC[(rowbase + l) * DXBC_ + h * HD_ + p]) * dts[l]);
    }
    if (tid == 0) {
        float r = 0.f;
        for (int l = 0; l < 64; ++l) { r += dts[l] * Ah; Acs[l] = r; }
        float alast = r;
        for (int l = 0; l < 64; ++l) decs[l] = expneg_(alast - Acs[l]);
        CDb[(((size_t)dir * B_ + b) * NH_ + h) * NC_ + c] = expneg_(alast);
    }
    __syncthreads();   // B2: Bs/Cs/Xt/Acs/decs ready

    for (int u = tid; u < 4096; u += 256) {
        int l = u >> 6, n = u & 63;
        Bt[n][l] = f2bs(bs2f(Bs[l][n]) * decs[l]);
    }
    __syncthreads();   // B3: Bt ready — no more barriers

    // ---- step 1: G = C B^T (this wave's 16-row strip) ----
    f32x4 a1[4];
#pragma unroll
    for (int ct = 0; ct < 4; ++ct) a1[ct] = (f32x4){0.f, 0.f, 0.f, 0.f};
#pragma unroll
    for (int ks = 0; ks < 2; ++ks) {
        short8 afr = *(const short8*)&Cs[16 * wave + ln15][ks * 32 + q * 8];
#pragma unroll
        for (int ct = 0; ct < 4; ++ct) {
            short8 bfr = *(const short8*)&Bs[16 * ct + ln15][ks * 32 + q * 8];
            a1[ct] = __builtin_amdgcn_mfma_f32_16x16x32_bf16(afr, bfr, a1[ct], 0, 0, 0);
        }
    }
    // ---- mask + decay -> M, written into Cs alias (own strip rows only) ----
#pragma unroll
    for (int ct = 0; ct < 4; ++ct)
#pragma unroll
        for (int rg = 0; rg < 4; ++rg) {
            int l = 16 * wave + 4 * q + rg, s = 16 * ct + ln15;
            float m = (s <= l) ? a1[ct][rg] * expneg_(Acs[l] - Acs[s]) : 0.f;
            Cs[l][s] = f2bs(m);
        }
    // ---- step 2: Yd = M @ Xdt ----
    f32x4 a2[4];
#pragma unroll
    for (int ct = 0; ct < 4; ++ct) a2[ct] = (f32x4){0.f, 0.f, 0.f, 0.f};
#pragma unroll
    for (int ks = 0; ks < 2; ++ks) {
        short8 afr = *(const short8*)&Cs[16 * wave + ln15][ks * 32 + q * 8];
#pragma unroll
        for (int ct = 0; ct < 4; ++ct) {
            short8 bfr = *(const short8*)&Xt[16 * ct + ln15][ks * 32 + q * 8];
            a2[ct] = __builtin_amdgcn_mfma_f32_16x16x32_bf16(afr, bfr, a2[ct], 0, 0, 0);
        }
    }
#pragma unroll
    for (int ct = 0; ct < 4; ++ct)
#pragma unroll
        for (int rg = 0; rg < 4; ++rg) {
            int l = 16 * wave + 4 * q + rg, p = 16 * ct + ln15;
            size_t tI = rowbase + l;
            float xraw = b2f(XBC[tI * DXBC_ + h * HD_ + p]);
            Y[tI * DI_ + h * HD_ + p] = f2b(a2[ct][rg] + Dh * xraw);
        }
    // ---- step 3: st[p][n] = sum_l Xt[p][l] * Bt[n][l] ----
    f32x4 a3[4];
#pragma unroll
    for (int ct = 0; ct < 4; ++ct) a3[ct] = (f32x4){0.f, 0.f, 0.f, 0.f};
#pragma unroll
    for (int ks = 0; ks < 2; ++ks) {
        short8 afr = *(const short8*)&Xt[16 * wave + ln15][ks * 32 + q * 8];
#pragma unroll
        for (int ct = 0; ct < 4; ++ct) {
            short8 bfr = *(const short8*)&Bt[16 * ct + ln15][ks * 32 + q * 8];
            a3[ct] = __builtin_amdgcn_mfma_f32_16x16x32_bf16(afr, bfr, a3[ct], 0, 0, 0);
        }
    }
    size_t sb = ((((size_t)dir * B_ + b) * NC_ + c) * NH_ + h) * 4096;
#pragma unroll
    for (int ct = 0; ct < 4; ++ct)
#pragma unroll
        for (int rg = 0; rg < 4; ++rg) {
            int p = 16 * wave + 4 * q + rg, n = 16 * ct + ln15;
            ST[sb + p * 64 + n] = f2b(a3[ct][rg]);
        }
}

// ---------------------------------------------------------------------------
// K3: inter-chunk scan, in place (ST[c] becomes the state BEFORE chunk c).
// grid: (64, 2), block 256, 16 state elements per thread, carry in f32.
// ---------------------------------------------------------------------------
__global__ __launch_bounds__(256) void k_scan(bf16* __restrict__ ST, const float* __restrict__ CDb)
{
    const int tid = threadIdx.x;
    const int dir = blockIdx.y;
    const int b = blockIdx.x >> 2, h = blockIdx.x & 3;
    const size_t cdbase = (((size_t)dir * B_ + b) * NH_ + h) * NC_;
    float carry[16];
#pragma unroll
    for (int q = 0; q < 16; ++q) carry[q] = 0.f;
    for (int c = 0; c < NC_; ++c) {
        const float cd = CDb[cdbase + c];
        size_t base = ((((size_t)dir * B_ + b) * NC_ + c) * NH_ + h) * 4096 + tid;
#pragma unroll
        for (int q = 0; q < 16; ++q) {
            float v = b2f(ST[base + q * 256]);
            ST[base + q * 256] = f2b(carry[q]);
            carry[q] = carry[q] * cd + v;
        }
    }
}

// ---------------------------------------------------------------------------
// K4 (MFMA): Y += exp(Acs[l]) * C @ prev^T. grid: (32, 16, 2), block 256.
// prev (ST) is [p][n] which is exactly the B-operand layout — no transpose.
// ---------------------------------------------------------------------------
__global__ __launch_bounds__(256) void k_offdiag_mfma(
    const bf16* __restrict__ XBC, const float* __restrict__ DTV,
    const float* __restrict__ AlF, const float* __restrict__ AlB,
    const bf16* __restrict__ ST, bf16* __restrict__ Y)
{
    const int tid = threadIdx.x;
    const int wave = tid >> 6, lane = tid & 63;
    const int ln15 = lane & 15, q = lane >> 4;
    const int c = blockIdx.x, b = blockIdx.y, dir = blockIdx.z;
    const float* Al = dir ? AlB : AlF;
    const int t0 = b * L_ + c * 64;
    const size_t rowbase = (size_t)dir * T_ + t0;

    __shared__ __align__(16) short Cs[64][72];
    __shared__ __align__(16) short Ps[64][72];
    __shared__ float Acs[64];

    for (int u = tid; u < 512; u += 256) {
        int r = u >> 3, g = u & 7;
        *(short8*)&Cs[r][g * 8] = *(const short8*)(XBC + (rowbase + r) * DXBC_ + 320 + g * 8);
    }

    for (int h = 0; h < NH_; ++h) {
        __syncthreads();   // prior-h Ps/Acs reads done; Cs ready (1st iter)
        if (tid == 0) {
            float A = -expf(Al[h]);
            float r = 0.f;
            for (int l = 0; l < 64; ++l) { r += DTV[(rowbase + l) * NH_ + h] * A; Acs[l] = r; }
        }
        size_t sb = ((((size_t)dir * B_ + b) * NC_ + c) * NH_ + h) * 4096;
        for (int u = tid; u < 512; u += 256) {
            int r = u >> 3, g = u & 7;
            *(short8*)&Ps[r][g * 8] = *(const short8*)(ST + sb + r * 64 + g * 8);
        }
        __syncthreads();

        f32x4 acc[4];
#pragma unroll
        for (int ct = 0; ct < 4; ++ct) acc[ct] = (f32x4){0.f, 0.f, 0.f, 0.f};
#pragma unroll
        for (int ks = 0; ks < 2; ++ks) {
            short8 afr = *(const short8*)&Cs[16 * wave + ln15][ks * 32 + q * 8];
#pragma unroll
            for (int ct = 0; ct < 4; ++ct) {
                short8 bfr = *(const short8*)&Ps[16 * ct + ln15][ks * 32 + q * 8];
                acc[ct] = __builtin_amdgcn_mfma_f32_16x16x32_bf16(afr, bfr, acc[ct], 0, 0, 0);
            }
        }
#pragma unroll
        for (int ct = 0; ct < 4; ++ct)
#pragma unroll
            for (int rg = 0; rg < 4; ++rg) {
                int l = 16 * wave + 4 * q + rg, p = 16 * ct + ln15;
                size_t gi = (rowbase + l) * DI_ + h * HD_ + p;
                Y[gi] = f2b(b2f(Y[gi]) + acc[ct][rg] * expneg_(Acs[l]));
            }
    }
}

// ---------------------------------------------------------------------------
// K5: y = Y * silu(z); RMSNorm over 256 channels; in place over Y.
// grid: (2048, 16, 2), block 256 (one token per block).
// ---------------------------------------------------------------------------
__global__ __launch_bounds__(256) void k_gate(
    const bf16* __restrict__ Z, const float* __restrict__ nwF, const float* __restrict__ nwB,
    bf16* __restrict__ Y)
{
    const int tid = threadIdx.x;
    const int t = blockIdx.y * L_ + blockIdx.x;
    const int dir = blockIdx.z;
    const float* nw = dir ? nwB : nwF;
    size_t gi = ((size_t)dir * T_ + t) * DI_ + tid;
    float v = b2f(Y[gi]);
    float zv = b2f(Z[gi]);
    v *= zv * sigmoidf_(zv);
    __shared__ float red[256];
    red[tid] = v * v;
    __syncthreads();
    for (int s = 128; s > 0; s >>= 1) {
        if (tid < s) red[tid] += red[tid + s];
        __syncthreads();
    }
    float r = rsqrtf(red[0] * (1.f / 256.f) + 1e-5f);
    Y[gi] = f2b(v * r * nw[tid]);
}

// ---------------------------------------------------------------------------
// K6 (MFMA): out[t] = y_f[t] @ Wo_f^T + y_b[flip(t)] @ Wo_b^T.
// grid 512, block 256 (4 waves); f32 accum across both dirs, f32 stores.
// ---------------------------------------------------------------------------
__global__ __launch_bounds__(256) void k_outproj_mfma(
    const bf16* __restrict__ Y, const float* __restrict__ WoF, const float* __restrict__ WoB,
    float* __restrict__ out)
{
    const int tid = threadIdx.x;
    const int wave = tid >> 6, lane = tid & 63;
    const int ln15 = lane & 15, q = lane >> 4;
    const int t0 = blockIdx.x * 64;
    const int batch = t0 >> 11;
    const int l0 = t0 & (L_ - 1);

    __shared__ __align__(16) short ys[64][72];
    __shared__ __align__(16) short wsm[128][72];

    f32x4 acc[8];
#pragma unroll
    for (int ct = 0; ct < 8; ++ct) acc[ct] = (f32x4){0.f, 0.f, 0.f, 0.f};

    for (int dir = 0; dir < 2; ++dir) {
        const float* Wo = dir ? WoB : WoF;
        for (int kt = 0; kt < 4; ++kt) {
            const int k0 = kt * 64;
            __syncthreads();
            for (int u = tid; u < 512; u += 256) {
                int r = u >> 3, g = u & 7;
                int tsrc = dir ? (batch * L_ + (L_ - 1 - (l0 + r))) : (t0 + r);
                *(short8*)&ys[r][g * 8] =
                    *(const short8*)(Y + ((size_t)dir * T_ + tsrc) * DI_ + k0 + g * 8);
            }
            for (int u = tid; u < 2048; u += 256) {
                int m = u >> 4, g = u & 15;
                float4 v = *(const float4*)&Wo[(size_t)m * DI_ + k0 + g * 4];
                S4 s; s.a = f2bs(v.x); s.b = f2bs(v.y); s.c = f2bs(v.z); s.d = f2bs(v.w);
                *(S4*)&wsm[m][g * 4] = s;
            }
            __syncthreads();
#pragma unroll
            for (int ks = 0; ks < 2; ++ks) {
                short8 afr = *(const short8*)&ys[16 * wave + ln15][ks * 32 + q * 8];
#pragma unroll
                for (int ct = 0; ct < 8; ++ct) {
                    short8 bfr = *(const short8*)&wsm[16 * ct + ln15][ks * 32 + q * 8];
                    acc[ct] = __builtin_amdgcn_mfma_f32_16x16x32_bf16(afr, bfr, acc[ct], 0, 0, 0);
                }
            }
        }
    }
#pragma unroll
    for (int ct = 0; ct < 8; ++ct)
#pragma unroll
        for (int rg = 0; rg < 4; ++rg) {
            int row = 16 * wave + 4 * q + rg, col = 16 * ct + ln15;
            out[((size_t)(t0 + row)) * DM_ + col] = acc[ct][rg];
        }
}

// ---------------------------------------------------------------------------
extern "C" void kernel_launch(void* const* d_in, const int* in_sizes, int n_in,
                              void* d_out, int out_size, void* d_ws, size_t ws_size,
                              hipStream_t stream)
{
    const float* x    = (const float*)d_in[0];
    const float* WiF  = (const float*)d_in[1];
    const float* cwF  = (const float*)d_in[2];
    const float* cbF  = (const float*)d_in[3];
    const float* dtbF = (const float*)d_in[4];
    const float* AlF  = (const float*)d_in[5];
    const float* DpF  = (const float*)d_in[6];
    const float* nwF  = (const float*)d_in[7];
    const float* WoF  = (const float*)d_in[8];
    const float* WiB  = (const float*)d_in[9];
    const float* cwB  = (const float*)d_in[10];
    const float* cbB  = (const float*)d_in[11];
    const float* dtbB = (const float*)d_in[12];
    const float* AlB  = (const float*)d_in[13];
    const float* DpB  = (const float*)d_in[14];
    const float* nwB  = (const float*)d_in[15];
    const float* WoB  = (const float*)d_in[16];

    // workspace layout: bf16 intermediates + f32 dt/decays (~152 MB)
    const size_t nZ   = (size_t)2 * T_ * DI_;       // bf16
    const size_t nXBC = (size_t)2 * T_ * DXBC_;     // bf16
    const size_t nY   = (size_t)2 * T_ * DI_;       // bf16
    const size_t nST  = (size_t)2 * B_ * NC_ * NH_ * HD_ * DS_;  // bf16
    const size_t nDTV = (size_t)2 * T_ * NH_;       // f32
    const size_t nCD  = (size_t)2 * B_ * NH_ * NC_; // f32
    const size_t need = (nZ + nXBC + nY + nST) * sizeof(bf16)
                      + (nDTV + nCD) * sizeof(float);
    if (ws_size < need) return;  // fail loudly (output stays poisoned)

    char* p = (char*)d_ws;
    bf16* Z    = (bf16*)p;            p += nZ * sizeof(bf16);
    bf16* XBC  = (bf16*)p;            p += nXBC * sizeof(bf16);
    bf16* Yb   = (bf16*)p;            p += nY * sizeof(bf16);
    bf16* ST   = (bf16*)p;            p += nST * sizeof(bf16);
    float* DTV = (float*)p;           p += nDTV * sizeof(float);
    float* CDb = (float*)p;

    k_inproj_mfma<<<dim3(512, 2), 256, 0, stream>>>(x, WiF, WiB, cwF, cbF, cwB, cbB,
                                                    dtbF, dtbB, Z, XBC, DTV);
    k_chunkdiag_mfma<<<dim3(NC_, B_ * NH_, 2), 256, 0, stream>>>(XBC, DTV, AlF, AlB, DpF, DpB,
                                                                 Yb, ST, CDb);
    k_scan<<<dim3(B_ * NH_, 2), 256, 0, stream>>>(ST, CDb);
    k_offdiag_mfma<<<dim3(NC_, B_, 2), 256, 0, stream>>>(XBC, DTV, AlF, AlB, ST, Yb);
    k_gate<<<dim3(L_, B_, 2), 256, 0, stream>>>(Z, nwF, nwB, Yb);
    k_outproj_mfma<<<dim3(512), 256, 0, stream>>>(Yb, WoF, WoB, (float*)d_out);
}

// Round 6
// 307.949 us; speedup vs baseline: 4.6518x; 1.1742x over previous
//
#include <hip/hip_runtime.h>
#include <hip/hip_bf16.h>
#include <cmath>

#define B_    16
#define L_    2048
#define T_    32768   // B_*L_
#define DM_   128
#define DI_   256
#define DXBC_ 384
#define DS_   64
#define HD_   64
#define NH_   4
#define NC_   32      // chunks per sequence (L_/64)

typedef __hip_bfloat16 bf16;
typedef __attribute__((ext_vector_type(8))) short short8;
typedef __attribute__((ext_vector_type(4))) float f32x4;

__device__ __forceinline__ float b2f(bf16 v) { return __bfloat162float(v); }
__device__ __forceinline__ bf16  f2b(float f) { return __float2bfloat16(f); }
__device__ __forceinline__ short f2bs(float f) { bf16 h = __float2bfloat16(f); return *reinterpret_cast<short*>(&h); }
__device__ __forceinline__ float bs2f(short s) { bf16 h = *reinterpret_cast<bf16*>(&s); return __bfloat162float(h); }
__device__ __forceinline__ float sigmoidf_(float x) { return 1.f / (1.f + expf(-x)); }
__device__ __forceinline__ float softplusf_(float x) { return (x > 20.f) ? x : log1pf(expf(x)); }
__device__ __forceinline__ float expneg_(float x) { return expf(fminf(x, 0.f)); }

struct __align__(8) S4 { short a, b, c, d; };

#define NWI 82432   // 644*128
#define NWO 32768   // 128*256

// ---------------------------------------------------------------------------
// K0: one-time f32 -> bf16 conversion of x, Wi_f/b, Wo_f/b.
// ---------------------------------------------------------------------------
__global__ __launch_bounds__(256) void k_prep(
    const float* __restrict__ x,
    const float* __restrict__ WiF, const float* __restrict__ WiB,
    const float* __restrict__ WoF, const float* __restrict__ WoB,
    bf16* __restrict__ Xb, bf16* __restrict__ WiFb, bf16* __restrict__ WiBb,
    bf16* __restrict__ WoFb, bf16* __restrict__ WoBb)
{
    const int gid = blockIdx.x * 256 + threadIdx.x;
    const int stride = gridDim.x * 256;
    for (int i = gid; i < (T_ * DM_ / 4) / 8; i += stride) { }  // (dummy-free; sizes below)
    for (int i = gid; i < T_ / 2 * DM_ / 64; i += stride) { }   // no-op guards removed below
    for (int i = gid; i < 1048576; i += stride) {               // 4,194,304 / 4
        float4 v = ((const float4*)x)[i];
        S4 s = { f2bs(v.x), f2bs(v.y), f2bs(v.z), f2bs(v.w) };
        ((S4*)Xb)[i] = s;
    }
    for (int i = gid; i < NWI / 4; i += stride) {
        float4 v = ((const float4*)WiF)[i];
        S4 s = { f2bs(v.x), f2bs(v.y), f2bs(v.z), f2bs(v.w) };
        ((S4*)WiFb)[i] = s;
        v = ((const float4*)WiB)[i];
        S4 t = { f2bs(v.x), f2bs(v.y), f2bs(v.z), f2bs(v.w) };
        ((S4*)WiBb)[i] = t;
    }
    for (int i = gid; i < NWO / 4; i += stride) {
        float4 v = ((const float4*)WoF)[i];
        S4 s = { f2bs(v.x), f2bs(v.y), f2bs(v.z), f2bs(v.w) };
        ((S4*)WoFb)[i] = s;
        v = ((const float4*)WoB)[i];
        S4 t = { f2bs(v.x), f2bs(v.y), f2bs(v.z), f2bs(v.w) };
        ((S4*)WoBb)[i] = t;
    }
}

// ---------------------------------------------------------------------------
// K1 (MFMA): in_proj GEMM from bf16 sources; fused conv1d+SiLU for xBC;
// dt via an 11th (zero-padded) col-tile. grid (512, 2), block 256 (4 waves).
// ---------------------------------------------------------------------------
__global__ __launch_bounds__(256) void k_inproj_mfma(
    const bf16* __restrict__ Xb, const bf16* __restrict__ WiFb, const bf16* __restrict__ WiBb,
    const float* __restrict__ cwF, const float* __restrict__ cbF,
    const float* __restrict__ cwB, const float* __restrict__ cbB,
    const float* __restrict__ dtbF, const float* __restrict__ dtbB,
    bf16* __restrict__ Z, bf16* __restrict__ XBC, float* __restrict__ DTV)
{
    const int tid  = threadIdx.x;
    const int wave = tid >> 6, lane = tid & 63;
    const int ln15 = lane & 15, q = lane >> 4;
    const int dir  = blockIdx.y;
    const bf16* Wi = dir ? WiBb : WiFb;
    const int t0 = blockIdx.x * 64;
    const int batch = t0 >> 11, l0 = t0 & (L_ - 1);
    const size_t rowbase = (size_t)dir * T_ + t0;

    __shared__ __align__(16) short xs[80][136];
    __shared__ __align__(16) char  smem[80 * 66 * 4];   // union: ws / raws
    short (*ws)[136]  = (short(*)[136])smem;
    float (*raws)[66] = (float(*)[66])smem;

    // stage A-tile (80 rows x 128) as pure short8 moves
    for (int u = tid; u < 1280; u += 256) {
        int r = u >> 4, g = u & 15;
        int l = l0 - 16 + r;
        short8 v = {0, 0, 0, 0, 0, 0, 0, 0};
        if (l >= 0) {
            int sl = dir ? (L_ - 1 - l) : l;
            v = *(const short8*)(Xb + ((size_t)batch * L_ + sl) * DM_ + g * 8);
        }
        *(short8*)&xs[r][g * 8] = v;
    }
    __syncthreads();

    for (int nt = 0; nt <= 10; ++nt) {
        const int c0 = nt * 64;
        __syncthreads();   // prior epilogue's raws reads complete
        if (nt < 10) {
            for (int u = tid; u < 1024; u += 256) {
                int r = u >> 4, g = u & 15;
                *(short8*)&ws[r][g * 8] = *(const short8*)(Wi + (size_t)(c0 + r) * DM_ + g * 8);
            }
        } else {   // dt tile: rows 640..643 real, rest zero
            for (int u = tid; u < 1024; u += 256) {
                int r = u >> 4, g = u & 15;
                short8 v = {0, 0, 0, 0, 0, 0, 0, 0};
                if (r < 4) v = *(const short8*)(Wi + (size_t)(640 + r) * DM_ + g * 8);
                *(short8*)&ws[r][g * 8] = v;
            }
        }
        __syncthreads();

        f32x4 acc[5];
#pragma unroll
        for (int mt = 0; mt < 5; ++mt) acc[mt] = (f32x4){0.f, 0.f, 0.f, 0.f};
#pragma unroll
        for (int ks = 0; ks < 4; ++ks) {
            short8 bfr = *(const short8*)&ws[16 * wave + ln15][ks * 32 + q * 8];
#pragma unroll
            for (int mt = 0; mt < 5; ++mt) {
                short8 afr = *(const short8*)&xs[16 * mt + ln15][ks * 32 + q * 8];
                acc[mt] = __builtin_amdgcn_mfma_f32_16x16x32_bf16(afr, bfr, acc[mt], 0, 0, 0);
            }
        }
        __syncthreads();   // ws reads done; raws may overwrite
#pragma unroll
        for (int mt = 0; mt < 5; ++mt)
#pragma unroll
            for (int rg = 0; rg < 4; ++rg)
                raws[16 * mt + 4 * q + rg][16 * wave + ln15] = acc[mt][rg];
        __syncthreads();

        if (nt < 4) {
            for (int u = tid; u < 1024; u += 256) {
                int row = u >> 4, c4 = (u & 15) * 4;
                S4 s = { f2bs(raws[16 + row][c4]),     f2bs(raws[16 + row][c4 + 1]),
                         f2bs(raws[16 + row][c4 + 2]), f2bs(raws[16 + row][c4 + 3]) };
                *(S4*)(Z + (rowbase + row) * DI_ + c0 + c4) = s;
            }
        } else if (nt < 10) {
            const float* cw = dir ? cwB : cwF;
            const float* cb = dir ? cbB : cbF;
            for (int u = tid; u < 1024; u += 256) {
                int row = u >> 4, c4 = (u & 15) * 4;
                short o[4];
#pragma unroll
                for (int j = 0; j < 4; ++j) {
                    int ch = c0 - 256 + c4 + j;
                    float s = cb[ch];
#pragma unroll
                    for (int k = 0; k < 4; ++k) s += raws[13 + row + k][c4 + j] * cw[ch * 4 + k];
                    s = s * sigmoidf_(s);
                    o[j] = f2bs(s);
                }
                S4 s4 = { o[0], o[1], o[2], o[3] };
                *(S4*)(XBC + (rowbase + row) * DXBC_ + c0 - 256 + c4) = s4;
            }
        } else {
            const float* dtb = dir ? dtbB : dtbF;
            int row = tid >> 2, cc = tid & 3;
            DTV[(rowbase + row) * NH_ + cc] = softplusf_(raws[16 + row][cc] + dtb[cc]);
        }
    }
}

// ---------------------------------------------------------------------------
// K2 (MFMA): per (chunk, b, h, dir): G = C B^T, mask+decay, Yd = M Xdt + D*x,
// chunk states st = (Xdt*dec)^T B. grid: (32, 64, 2), block 256 (4 waves).
// ---------------------------------------------------------------------------
__global__ __launch_bounds__(256) void k_chunkdiag_mfma(
    const bf16* __restrict__ XBC, const float* __restrict__ DTV,
    const float* __restrict__ AlF, const float* __restrict__ AlB,
    const float* __restrict__ DpF, const float* __restrict__ DpB,
    bf16* __restrict__ Y, bf16* __restrict__ ST, float* __restrict__ CDb)
{
    const int tid = threadIdx.x;
    const int wave = tid >> 6, lane = tid & 63;
    const int ln15 = lane & 15, q = lane >> 4;
    const int c = blockIdx.x;
    const int b = blockIdx.y >> 2;
    const int h = blockIdx.y & 3;
    const int dir = blockIdx.z;
    const float Ah = -expf((dir ? AlB : AlF)[h]);
    const float Dh = (dir ? DpB : DpF)[h];
    const int t0 = b * L_ + c * 64;
    const size_t rowbase = (size_t)dir * T_ + t0;

    __shared__ __align__(16) short Bs[64][72];
    __shared__ __align__(16) short Cs[64][72];   // aliased as M after step 1
    __shared__ __align__(16) short Xt[64][72];   // Xdt transposed: Xt[p][l]
    __shared__ __align__(16) short Bt[64][72];   // Bt[n][l] = dec[l]*B[l][n]
    __shared__ float dts[64];
    __shared__ float Acs[64];
    __shared__ float decs[64];

    if (tid < 64) dts[tid] = DTV[(rowbase + tid) * NH_ + h];
    __syncthreads();   // B1: dts ready

    for (int u = tid; u < 512; u += 256) {
        int r = u >> 3, g = u & 7;
        size_t base = (rowbase + r) * DXBC_;
        *(short8*)&Bs[r][g * 8] = *(const short8*)(XBC + base + 256 + g * 8);
        *(short8*)&Cs[r][g * 8] = *(const short8*)(XBC + base + 320 + g * 8);
    }
    for (int u = tid; u < 4096; u += 256) {
        int l = u >> 6, p = u & 63;
        Xt[p][l] = f2bs(b2f(XBC[(rowbase + l) * DXBC_ + h * HD_ + p]) * dts[l]);
    }
    if (tid == 0) {
        float r = 0.f;
        for (int l = 0; l < 64; ++l) { r += dts[l] * Ah; Acs[l] = r; }
        float alast = r;
        for (int l = 0; l < 64; ++l) decs[l] = expneg_(alast - Acs[l]);
        CDb[(((size_t)dir * B_ + b) * NH_ + h) * NC_ + c] = expneg_(alast);
    }
    __syncthreads();   // B2

    for (int u = tid; u < 4096; u += 256) {
        int l = u >> 6, n = u & 63;
        Bt[n][l] = f2bs(bs2f(Bs[l][n]) * decs[l]);
    }
    __syncthreads();   // B3

    // step 1: G = C B^T
    f32x4 a1[4];
#pragma unroll
    for (int ct = 0; ct < 4; ++ct) a1[ct] = (f32x4){0.f, 0.f, 0.f, 0.f};
#pragma unroll
    for (int ks = 0; ks < 2; ++ks) {
        short8 afr = *(const short8*)&Cs[16 * wave + ln15][ks * 32 + q * 8];
#pragma unroll
        for (int ct = 0; ct < 4; ++ct) {
            short8 bfr = *(const short8*)&Bs[16 * ct + ln15][ks * 32 + q * 8];
            a1[ct] = __builtin_amdgcn_mfma_f32_16x16x32_bf16(afr, bfr, a1[ct], 0, 0, 0);
        }
    }
#pragma unroll
    for (int ct = 0; ct < 4; ++ct)
#pragma unroll
        for (int rg = 0; rg < 4; ++rg) {
            int l = 16 * wave + 4 * q + rg, s = 16 * ct + ln15;
            float m = (s <= l) ? a1[ct][rg] * expneg_(Acs[l] - Acs[s]) : 0.f;
            Cs[l][s] = f2bs(m);
        }
    // step 2: Yd = M @ Xdt
    f32x4 a2[4];
#pragma unroll
    for (int ct = 0; ct < 4; ++ct) a2[ct] = (f32x4){0.f, 0.f, 0.f, 0.f};
#pragma unroll
    for (int ks = 0; ks < 2; ++ks) {
        short8 afr = *(const short8*)&Cs[16 * wave + ln15][ks * 32 + q * 8];
#pragma unroll
        for (int ct = 0; ct < 4; ++ct) {
            short8 bfr = *(const short8*)&Xt[16 * ct + ln15][ks * 32 + q * 8];
            a2[ct] = __builtin_amdgcn_mfma_f32_16x16x32_bf16(afr, bfr, a2[ct], 0, 0, 0);
        }
    }
#pragma unroll
    for (int ct = 0; ct < 4; ++ct)
#pragma unroll
        for (int rg = 0; rg < 4; ++rg) {
            int l = 16 * wave + 4 * q + rg, p = 16 * ct + ln15;
            size_t tI = rowbase + l;
            float xraw = b2f(XBC[tI * DXBC_ + h * HD_ + p]);
            Y[tI * DI_ + h * HD_ + p] = f2b(a2[ct][rg] + Dh * xraw);
        }
    // step 3: st[p][n]
    f32x4 a3[4];
#pragma unroll
    for (int ct = 0; ct < 4; ++ct) a3[ct] = (f32x4){0.f, 0.f, 0.f, 0.f};
#pragma unroll
    for (int ks = 0; ks < 2; ++ks) {
        short8 afr = *(const short8*)&Xt[16 * wave + ln15][ks * 32 + q * 8];
#pragma unroll
        for (int ct = 0; ct < 4; ++ct) {
            short8 bfr = *(const short8*)&Bt[16 * ct + ln15][ks * 32 + q * 8];
            a3[ct] = __builtin_amdgcn_mfma_f32_16x16x32_bf16(afr, bfr, a3[ct], 0, 0, 0);
        }
    }
    size_t sb = ((((size_t)dir * B_ + b) * NC_ + c) * NH_ + h) * 4096;
#pragma unroll
    for (int ct = 0; ct < 4; ++ct)
#pragma unroll
        for (int rg = 0; rg < 4; ++rg) {
            int p = 16 * wave + 4 * q + rg, n = 16 * ct + ln15;
            ST[sb + p * 64 + n] = f2b(a3[ct][rg]);
        }
}

// ---------------------------------------------------------------------------
// K3: inter-chunk scan, in place. grid (256, 2), block 256, 4 els/thread.
// ---------------------------------------------------------------------------
__global__ __launch_bounds__(256) void k_scan(bf16* __restrict__ ST, const float* __restrict__ CDb)
{
    const int tid = threadIdx.x;
    const int dir = blockIdx.y;
    const int bx = blockIdx.x;
    const int b = bx >> 4, h = (bx >> 2) & 3, qt = bx & 3;
    const size_t cdbase = (((size_t)dir * B_ + b) * NH_ + h) * NC_;
    float carry[4] = {0.f, 0.f, 0.f, 0.f};
    for (int c = 0; c < NC_; ++c) {
        const float cd = CDb[cdbase + c];
        size_t base = ((((size_t)dir * B_ + b) * NC_ + c) * NH_ + h) * 4096 + qt * 1024 + tid;
#pragma unroll
        for (int q = 0; q < 4; ++q) {
            float v = b2f(ST[base + q * 256]);
            ST[base + q * 256] = f2b(carry[q]);
            carry[q] = carry[q] * cd + v;
        }
    }
}

// ---------------------------------------------------------------------------
// K4 (MFMA, fused gate+RMSNorm): Yfinal = rmsnorm((Yd + offdiag) * silu(z)) * nw.
// grid: (32, 16, 2), block 256. Block covers 64 tokens x all 256 channels.
// ---------------------------------------------------------------------------
__global__ __launch_bounds__(256) void k_offdiag_fused(
    const bf16* __restrict__ XBC, const float* __restrict__ DTV,
    const float* __restrict__ AlF, const float* __restrict__ AlB,
    const bf16* __restrict__ ST, const bf16* __restrict__ Z,
    const float* __restrict__ nwF, const float* __restrict__ nwB,
    bf16* __restrict__ Y)
{
    const int tid = threadIdx.x;
    const int wave = tid >> 6, lane = tid & 63;
    const int ln15 = lane & 15, q = lane >> 4;
    const int c = blockIdx.x, b = blockIdx.y, dir = blockIdx.z;
    const float* Al = dir ? AlB : AlF;
    const int t0 = b * L_ + c * 64;
    const size_t rowbase = (size_t)dir * T_ + t0;

    __shared__ __align__(16) short Cs[64][72];
    __shared__ __align__(16) short Ps[64][72];
    __shared__ __align__(16) short Yz[64][264];
    __shared__ float Acs[64];

    for (int u = tid; u < 512; u += 256) {
        int r = u >> 3, g = u & 7;
        *(short8*)&Cs[r][g * 8] = *(const short8*)(XBC + (rowbase + r) * DXBC_ + 320 + g * 8);
    }
    // stage diag-Y tile (coalesced)
    for (int u = tid; u < 2048; u += 256) {
        int r = u >> 5, g = u & 31;
        *(short8*)&Yz[r][g * 8] = *(const short8*)(Y + (rowbase + r) * DI_ + g * 8);
    }

    for (int h = 0; h < NH_; ++h) {
        __syncthreads();
        if (tid == 0) {
            float A = -expf(Al[h]);
            float r = 0.f;
            for (int l = 0; l < 64; ++l) { r += DTV[(rowbase + l) * NH_ + h] * A; Acs[l] = r; }
        }
        size_t sb = ((((size_t)dir * B_ + b) * NC_ + c) * NH_ + h) * 4096;
        for (int u = tid; u < 512; u += 256) {
            int r = u >> 3, g = u & 7;
            *(short8*)&Ps[r][g * 8] = *(const short8*)(ST + sb + r * 64 + g * 8);
        }
        __syncthreads();

        f32x4 acc[4];
#pragma unroll
        for (int ct = 0; ct < 4; ++ct) acc[ct] = (f32x4){0.f, 0.f, 0.f, 0.f};
#pragma unroll
        for (int ks = 0; ks < 2; ++ks) {
            short8 afr = *(const short8*)&Cs[16 * wave + ln15][ks * 32 + q * 8];
#pragma unroll
            for (int ct = 0; ct < 4; ++ct) {
                short8 bfr = *(const short8*)&Ps[16 * ct + ln15][ks * 32 + q * 8];
                acc[ct] = __builtin_amdgcn_mfma_f32_16x16x32_bf16(afr, bfr, acc[ct], 0, 0, 0);
            }
        }
        // accumulate into Yz (each wave touches only its own 16 rows; cols unique per h)
#pragma unroll
        for (int ct = 0; ct < 4; ++ct)
#pragma unroll
            for (int rg = 0; rg < 4; ++rg) {
                int l = 16 * wave + 4 * q + rg, p = 16 * ct + ln15;
                float yv = bs2f(Yz[l][h * 64 + p]) + acc[ct][rg] * expneg_(Acs[l]);
                Yz[l][h * 64 + p] = f2bs(yv);
            }
    }
    __syncthreads();

    // gate + RMSNorm epilogue: wave w handles rows 16w..16w+15; lane covers 4 cols
    const float* nw = dir ? nwB : nwF;
    float nwv[4];
#pragma unroll
    for (int j = 0; j < 4; ++j) nwv[j] = nw[lane * 4 + j];
    for (int rr = 0; rr < 16; ++rr) {
        int row = 16 * wave + rr;
        S4 zv4 = *(const S4*)(Z + (rowbase + row) * DI_ + lane * 4);
        short zr[4] = { zv4.a, zv4.b, zv4.c, zv4.d };
        float v[4]; float ss = 0.f;
#pragma unroll
        for (int j = 0; j < 4; ++j) {
            float yv = bs2f(Yz[row][lane * 4 + j]);
            float zf = bs2f(zr[j]);
            v[j] = yv * zf * sigmoidf_(zf);
            ss += v[j] * v[j];
        }
#pragma unroll
        for (int off = 1; off < 64; off <<= 1) ss += __shfl_xor(ss, off);
        float rn = rsqrtf(ss * (1.f / 256.f) + 1e-5f);
        S4 o = { f2bs(v[0] * rn * nwv[0]), f2bs(v[1] * rn * nwv[1]),
                 f2bs(v[2] * rn * nwv[2]), f2bs(v[3] * rn * nwv[3]) };
        *(S4*)(Y + (rowbase + row) * DI_ + lane * 4) = o;
    }
}

// ---------------------------------------------------------------------------
// K6 (MFMA): out[t] = y_f[t] @ Wo_f^T + y_b[flip(t)] @ Wo_b^T (bf16 weights).
// ---------------------------------------------------------------------------
__global__ __launch_bounds__(256) void k_outproj_mfma(
    const bf16* __restrict__ Y, const bf16* __restrict__ WoFb, const bf16* __restrict__ WoBb,
    float* __restrict__ out)
{
    const int tid = threadIdx.x;
    const int wave = tid >> 6, lane = tid & 63;
    const int ln15 = lane & 15, q = lane >> 4;
    const int t0 = blockIdx.x * 64;
    const int batch = t0 >> 11;
    const int l0 = t0 & (L_ - 1);

    __shared__ __align__(16) short ys[64][72];
    __shared__ __align__(16) short wsm[128][72];

    f32x4 acc[8];
#pragma unroll
    for (int ct = 0; ct < 8; ++ct) acc[ct] = (f32x4){0.f, 0.f, 0.f, 0.f};

    for (int dir = 0; dir < 2; ++dir) {
        const bf16* Wo = dir ? WoBb : WoFb;
        for (int kt = 0; kt < 4; ++kt) {
            const int k0 = kt * 64;
            __syncthreads();
            for (int u = tid; u < 512; u += 256) {
                int r = u >> 3, g = u & 7;
                int tsrc = dir ? (batch * L_ + (L_ - 1 - (l0 + r))) : (t0 + r);
                *(short8*)&ys[r][g * 8] =
                    *(const short8*)(Y + ((size_t)dir * T_ + tsrc) * DI_ + k0 + g * 8);
            }
            for (int u = tid; u < 1024; u += 256) {
                int m = u >> 3, g = u & 7;
                *(short8*)&wsm[m][g * 8] = *(const short8*)(Wo + (size_t)m * DI_ + k0 + g * 8);
            }
            __syncthreads();
#pragma unroll
            for (int ks = 0; ks < 2; ++ks) {
                short8 afr = *(const short8*)&ys[16 * wave + ln15][ks * 32 + q * 8];
#pragma unroll
                for (int ct = 0; ct < 8; ++ct) {
                    short8 bfr = *(const short8*)&wsm[16 * ct + ln15][ks * 32 + q * 8];
                    acc[ct] = __builtin_amdgcn_mfma_f32_16x16x32_bf16(afr, bfr, acc[ct], 0, 0, 0);
                }
            }
        }
    }
#pragma unroll
    for (int ct = 0; ct < 8; ++ct)
#pragma unroll
        for (int rg = 0; rg < 4; ++rg) {
            int row = 16 * wave + 4 * q + rg, col = 16 * ct + ln15;
            out[((size_t)(t0 + row)) * DM_ + col] = acc[ct][rg];
        }
}

// ---------------------------------------------------------------------------
extern "C" void kernel_launch(void* const* d_in, const int* in_sizes, int n_in,
                              void* d_out, int out_size, void* d_ws, size_t ws_size,
                              hipStream_t stream)
{
    const float* x    = (const float*)d_in[0];
    const float* WiF  = (const float*)d_in[1];
    const float* cwF  = (const float*)d_in[2];
    const float* cbF  = (const float*)d_in[3];
    const float* dtbF = (const float*)d_in[4];
    const float* AlF  = (const float*)d_in[5];
    const float* DpF  = (const float*)d_in[6];
    const float* nwF  = (const float*)d_in[7];
    const float* WoF  = (const float*)d_in[8];
    const float* WiB  = (const float*)d_in[9];
    const float* cwB  = (const float*)d_in[10];
    const float* cbB  = (const float*)d_in[11];
    const float* dtbB = (const float*)d_in[12];
    const float* AlB  = (const float*)d_in[13];
    const float* DpB  = (const float*)d_in[14];
    const float* nwB  = (const float*)d_in[15];
    const float* WoB  = (const float*)d_in[16];

    const size_t nZ   = (size_t)2 * T_ * DI_;       // bf16
    const size_t nXBC = (size_t)2 * T_ * DXBC_;     // bf16
    const size_t nY   = (size_t)2 * T_ * DI_;       // bf16
    const size_t nST  = (size_t)2 * B_ * NC_ * NH_ * HD_ * DS_;  // bf16
    const size_t nWb  = (size_t)2 * NWI + 2 * NWO;  // bf16 weight copies
    const size_t nDTV = (size_t)2 * T_ * NH_;       // f32
    const size_t nCD  = (size_t)2 * B_ * NH_ * NC_; // f32
    const size_t need = (nZ + nXBC + nY + nST + nWb) * sizeof(bf16)
                      + (nDTV + nCD) * sizeof(float);
    if (ws_size < need) return;

    char* p = (char*)d_ws;
    bf16* Z    = (bf16*)p;            p += nZ * sizeof(bf16);
    bf16* XBC  = (bf16*)p;            p += nXBC * sizeof(bf16);
    bf16* Yb   = (bf16*)p;            p += nY * sizeof(bf16);
    bf16* ST   = (bf16*)p;            p += nST * sizeof(bf16);
    bf16* WiFb = (bf16*)p;            p += (size_t)NWI * sizeof(bf16);
    bf16* WiBb = (bf16*)p;            p += (size_t)NWI * sizeof(bf16);
    bf16* WoFb = (bf16*)p;            p += (size_t)NWO * sizeof(bf16);
    bf16* WoBb = (bf16*)p;            p += (size_t)NWO * sizeof(bf16);
    float* DTV = (float*)p;           p += nDTV * sizeof(float);
    float* CDb = (float*)p;
    bf16* Xb   = ST;   // alias: Xb dead before ST is written (k_chunkdiag)

    k_prep<<<2048, 256, 0, stream>>>(x, WiF, WiB, WoF, WoB, Xb, WiFb, WiBb, WoFb, WoBb);
    k_inproj_mfma<<<dim3(512, 2), 256, 0, stream>>>(Xb, WiFb, WiBb, cwF, cbF, cwB, cbB,
                                                    dtbF, dtbB, Z, XBC, DTV);
    k_chunkdiag_mfma<<<dim3(NC_, B_ * NH_, 2), 256, 0, stream>>>(XBC, DTV, AlF, AlB, DpF, DpB,
                                                                 Yb, ST, CDb);
    k_scan<<<dim3(256, 2), 256, 0, stream>>>(ST, CDb);
    k_offdiag_fused<<<dim3(NC_, B_, 2), 256, 0, stream>>>(XBC, DTV, AlF, AlB, ST, Z,
                                                          nwF, nwB, Yb);
    k_outproj_mfma<<<dim3(512), 256, 0, stream>>>(Yb, WoFb, WoBb, (float*)d_out);
}

// Round 7
// 285.643 us; speedup vs baseline: 5.0151x; 1.0781x over previous
//
#include <hip/hip_runtime.h>
#include <hip/hip_bf16.h>
#include <cmath>

#define B_    16
#define L_    2048
#define T_    32768   // B_*L_
#define DM_   128
#define DI_   256
#define DXBC_ 384
#define DS_   64
#define HD_   64
#define NH_   4
#define NC_   32      // chunks per sequence (L_/64)

typedef __hip_bfloat16 bf16;
typedef __attribute__((ext_vector_type(8))) short short8;
typedef __attribute__((ext_vector_type(4))) float f32x4;

__device__ __forceinline__ float b2f(bf16 v) { return __bfloat162float(v); }
__device__ __forceinline__ bf16  f2b(float f) { return __float2bfloat16(f); }
__device__ __forceinline__ short f2bs(float f) { bf16 h = __float2bfloat16(f); return *reinterpret_cast<short*>(&h); }
__device__ __forceinline__ float bs2f(short s) { bf16 h = *reinterpret_cast<bf16*>(&s); return __bfloat162float(h); }
__device__ __forceinline__ float sigmoidf_(float x) { return 1.f / (1.f + expf(-x)); }
__device__ __forceinline__ float softplusf_(float x) { return (x > 20.f) ? x : log1pf(expf(x)); }
__device__ __forceinline__ float expneg_(float x) { return expf(fminf(x, 0.f)); }

struct __align__(8) S4 { short a, b, c, d; };

#define NWI 82432   // 644*128
#define NWO 32768   // 128*256

// ---------------------------------------------------------------------------
// K0: one-time f32 -> bf16 conversion of x, Wi_f/b, Wo_f/b.
// ---------------------------------------------------------------------------
__global__ __launch_bounds__(256) void k_prep(
    const float* __restrict__ x,
    const float* __restrict__ WiF, const float* __restrict__ WiB,
    const float* __restrict__ WoF, const float* __restrict__ WoB,
    bf16* __restrict__ Xb, bf16* __restrict__ WiFb, bf16* __restrict__ WiBb,
    bf16* __restrict__ WoFb, bf16* __restrict__ WoBb)
{
    const int gid = blockIdx.x * 256 + threadIdx.x;
    const int stride = gridDim.x * 256;
    for (int i = gid; i < 1048576; i += stride) {   // T_*DM_/4
        float4 v = ((const float4*)x)[i];
        S4 s = { f2bs(v.x), f2bs(v.y), f2bs(v.z), f2bs(v.w) };
        ((S4*)Xb)[i] = s;
    }
    for (int i = gid; i < NWI / 4; i += stride) {
        float4 v = ((const float4*)WiF)[i];
        S4 s = { f2bs(v.x), f2bs(v.y), f2bs(v.z), f2bs(v.w) };
        ((S4*)WiFb)[i] = s;
        v = ((const float4*)WiB)[i];
        S4 t = { f2bs(v.x), f2bs(v.y), f2bs(v.z), f2bs(v.w) };
        ((S4*)WiBb)[i] = t;
    }
    for (int i = gid; i < NWO / 4; i += stride) {
        float4 v = ((const float4*)WoF)[i];
        S4 s = { f2bs(v.x), f2bs(v.y), f2bs(v.z), f2bs(v.w) };
        ((S4*)WoFb)[i] = s;
        v = ((const float4*)WoB)[i];
        S4 t = { f2bs(v.x), f2bs(v.y), f2bs(v.z), f2bs(v.w) };
        ((S4*)WoBb)[i] = t;
    }
}

// ---------------------------------------------------------------------------
// K1 (MFMA): in_proj GEMM from bf16 sources; fused conv1d+SiLU for xBC;
// dt tile stored straight from accumulators. grid (512, 2), block 256.
// LDS: xs 21.25KB + union(ws 17KB / raws bf16 11.25KB) = 38.3KB -> 4 blk/CU.
// ---------------------------------------------------------------------------
__global__ __launch_bounds__(256) void k_inproj_mfma(
    const bf16* __restrict__ Xb, const bf16* __restrict__ WiFb, const bf16* __restrict__ WiBb,
    const float* __restrict__ cwF, const float* __restrict__ cbF,
    const float* __restrict__ cwB, const float* __restrict__ cbB,
    const float* __restrict__ dtbF, const float* __restrict__ dtbB,
    bf16* __restrict__ Z, bf16* __restrict__ XBC, float* __restrict__ DTV)
{
    const int tid  = threadIdx.x;
    const int wave = tid >> 6, lane = tid & 63;
    const int ln15 = lane & 15, q = lane >> 4;
    const int dir  = blockIdx.y;
    const bf16* Wi = dir ? WiBb : WiFb;
    const int t0 = blockIdx.x * 64;
    const int batch = t0 >> 11, l0 = t0 & (L_ - 1);
    const size_t rowbase = (size_t)dir * T_ + t0;

    __shared__ __align__(16) short xs[80][136];
    __shared__ __align__(16) short smem2[64 * 136];   // union: ws[64][136] / raws[80][72]
    short (*ws)[136]  = (short(*)[136])smem2;
    short (*raws)[72] = (short(*)[72])smem2;

    // stage A-tile (80 rows x 128) as pure short8 moves
    for (int u = tid; u < 1280; u += 256) {
        int r = u >> 4, g = u & 15;
        int l = l0 - 16 + r;
        short8 v = {0, 0, 0, 0, 0, 0, 0, 0};
        if (l >= 0) {
            int sl = dir ? (L_ - 1 - l) : l;
            v = *(const short8*)(Xb + ((size_t)batch * L_ + sl) * DM_ + g * 8);
        }
        *(short8*)&xs[r][g * 8] = v;
    }
    __syncthreads();

    for (int nt = 0; nt <= 10; ++nt) {
        const int c0 = nt * 64;
        __syncthreads();   // prior epilogue's raws reads done
        if (nt < 10) {
            for (int u = tid; u < 1024; u += 256) {
                int r = u >> 4, g = u & 15;
                *(short8*)&ws[r][g * 8] = *(const short8*)(Wi + (size_t)(c0 + r) * DM_ + g * 8);
            }
        } else {   // dt tile: rows 640..643 real, rest zero
            for (int u = tid; u < 1024; u += 256) {
                int r = u >> 4, g = u & 15;
                short8 v = {0, 0, 0, 0, 0, 0, 0, 0};
                if (r < 4) v = *(const short8*)(Wi + (size_t)(640 + r) * DM_ + g * 8);
                *(short8*)&ws[r][g * 8] = v;
            }
        }
        __syncthreads();

        f32x4 acc[5];
#pragma unroll
        for (int mt = 0; mt < 5; ++mt) acc[mt] = (f32x4){0.f, 0.f, 0.f, 0.f};
#pragma unroll
        for (int ks = 0; ks < 4; ++ks) {
            short8 bfr = *(const short8*)&ws[16 * wave + ln15][ks * 32 + q * 8];
#pragma unroll
            for (int mt = 0; mt < 5; ++mt) {
                short8 afr = *(const short8*)&xs[16 * mt + ln15][ks * 32 + q * 8];
                acc[mt] = __builtin_amdgcn_mfma_f32_16x16x32_bf16(afr, bfr, acc[mt], 0, 0, 0);
            }
        }

        if (nt == 10) {
            // DTV straight from accumulators (wave 0 holds cols 0..15)
            if (wave == 0 && ln15 < 4) {
                const float* dtb = dir ? dtbB : dtbF;
                float bias = dtb[ln15];
#pragma unroll
                for (int mt = 1; mt < 5; ++mt)
#pragma unroll
                    for (int rg = 0; rg < 4; ++rg) {
                        int row = 16 * (mt - 1) + 4 * q + rg;
                        DTV[(rowbase + row) * NH_ + ln15] = softplusf_(acc[mt][rg] + bias);
                    }
            }
            break;
        }

        __syncthreads();   // ws reads done; raws may overwrite
#pragma unroll
        for (int mt = 0; mt < 5; ++mt)
#pragma unroll
            for (int rg = 0; rg < 4; ++rg)
                raws[16 * mt + 4 * q + rg][16 * wave + ln15] = f2bs(acc[mt][rg]);
        __syncthreads();

        if (nt < 4) {
            // z columns: straight bf16 copy, S4-packed
            for (int u = tid; u < 1024; u += 256) {
                int row = u >> 4, c4 = (u & 15) * 4;
                S4 s = *(const S4*)&raws[16 + row][c4];
                *(S4*)(Z + (rowbase + row) * DI_ + c0 + c4) = s;
            }
        } else {
            const float* cw = dir ? cwB : cwF;
            const float* cb = dir ? cbB : cbF;
            for (int u = tid; u < 1024; u += 256) {
                int row = u >> 4, c4 = (u & 15) * 4;
                short o[4];
#pragma unroll
                for (int j = 0; j < 4; ++j) {
                    int ch = c0 - 256 + c4 + j;
                    float s = cb[ch];
#pragma unroll
                    for (int k = 0; k < 4; ++k) s += bs2f(raws[13 + row + k][c4 + j]) * cw[ch * 4 + k];
                    s = s * sigmoidf_(s);
                    o[j] = f2bs(s);
                }
                S4 s4 = { o[0], o[1], o[2], o[3] };
                *(S4*)(XBC + (rowbase + row) * DXBC_ + c0 - 256 + c4) = s4;
            }
        }
    }
}

// ---------------------------------------------------------------------------
// K2 (MFMA): per (chunk, b, h, dir): G = C B^T, mask+decay, Yd = M Xdt + D*x,
// chunk states st = (Xdt*dec)^T B. grid: (32, 64, 2), block 256, 2 barriers.
// ---------------------------------------------------------------------------
__global__ __launch_bounds__(256) void k_chunkdiag_mfma(
    const bf16* __restrict__ XBC, const float* __restrict__ DTV,
    const float* __restrict__ AlF, const float* __restrict__ AlB,
    const float* __restrict__ DpF, const float* __restrict__ DpB,
    bf16* __restrict__ Y, bf16* __restrict__ ST, float* __restrict__ CDb)
{
    const int tid = threadIdx.x;
    const int wave = tid >> 6, lane = tid & 63;
    const int ln15 = lane & 15, q = lane >> 4;
    const int c = blockIdx.x;
    const int b = blockIdx.y >> 2;
    const int h = blockIdx.y & 3;
    const int dir = blockIdx.z;
    const float Ah = -expf((dir ? AlB : AlF)[h]);
    const float Dh = (dir ? DpB : DpF)[h];
    const int t0 = b * L_ + c * 64;
    const size_t rowbase = (size_t)dir * T_ + t0;

    __shared__ __align__(16) short Bs[64][72];
    __shared__ __align__(16) short Cs[64][72];   // aliased as M after step 1
    __shared__ __align__(16) short Xt[64][72];   // Xdt transposed: Xt[p][l]
    __shared__ __align__(16) short Bt[64][72];   // Bt[n][l] = dec[l]*B[l][n]
    __shared__ float dts[64];
    __shared__ float Acs[64];
    __shared__ float decs[64];

    // wave-0 shuffle scan for Acs/decs
    if (tid < 64) {
        int l = tid;
        float dt = DTV[(rowbase + l) * NH_ + h];
        dts[l] = dt;
        float s = dt * Ah;
#pragma unroll
        for (int off = 1; off < 64; off <<= 1) {
            float t2 = __shfl_up(s, off);
            if (l >= off) s += t2;
        }
        Acs[l] = s;
        float alast = __shfl(s, 63);
        decs[l] = expneg_(alast - s);
        if (l == 0) CDb[(((size_t)dir * B_ + b) * NH_ + h) * NC_ + c] = expneg_(alast);
    }
    __syncthreads();   // B1

    for (int u = tid; u < 512; u += 256) {
        int r = u >> 3, g = u & 7;
        size_t base = (rowbase + r) * DXBC_;
        *(short8*)&Bs[r][g * 8] = *(const short8*)(XBC + base + 256 + g * 8);
        *(short8*)&Cs[r][g * 8] = *(const short8*)(XBC + base + 320 + g * 8);
    }
    for (int u = tid; u < 4096; u += 256) {
        int l = u >> 6, p = u & 63;
        Xt[p][l] = f2bs(b2f(XBC[(rowbase + l) * DXBC_ + h * HD_ + p]) * dts[l]);
    }
    for (int u = tid; u < 4096; u += 256) {
        int l = u >> 6, n = u & 63;
        Bt[n][l] = f2bs(b2f(XBC[(rowbase + l) * DXBC_ + 256 + n]) * decs[l]);
    }
    __syncthreads();   // B2 — last barrier

    // step 1: G = C B^T
    f32x4 a1[4];
#pragma unroll
    for (int ct = 0; ct < 4; ++ct) a1[ct] = (f32x4){0.f, 0.f, 0.f, 0.f};
#pragma unroll
    for (int ks = 0; ks < 2; ++ks) {
        short8 afr = *(const short8*)&Cs[16 * wave + ln15][ks * 32 + q * 8];
#pragma unroll
        for (int ct = 0; ct < 4; ++ct) {
            short8 bfr = *(const short8*)&Bs[16 * ct + ln15][ks * 32 + q * 8];
            a1[ct] = __builtin_amdgcn_mfma_f32_16x16x32_bf16(afr, bfr, a1[ct], 0, 0, 0);
        }
    }
#pragma unroll
    for (int ct = 0; ct < 4; ++ct)
#pragma unroll
        for (int rg = 0; rg < 4; ++rg) {
            int l = 16 * wave + 4 * q + rg, s = 16 * ct + ln15;
            float m = (s <= l) ? a1[ct][rg] * expneg_(Acs[l] - Acs[s]) : 0.f;
            Cs[l][s] = f2bs(m);   // own wave strip only
        }
    // step 2: Yd = M @ Xdt
    f32x4 a2[4];
#pragma unroll
    for (int ct = 0; ct < 4; ++ct) a2[ct] = (f32x4){0.f, 0.f, 0.f, 0.f};
#pragma unroll
    for (int ks = 0; ks < 2; ++ks) {
        short8 afr = *(const short8*)&Cs[16 * wave + ln15][ks * 32 + q * 8];
#pragma unroll
        for (int ct = 0; ct < 4; ++ct) {
            short8 bfr = *(const short8*)&Xt[16 * ct + ln15][ks * 32 + q * 8];
            a2[ct] = __builtin_amdgcn_mfma_f32_16x16x32_bf16(afr, bfr, a2[ct], 0, 0, 0);
        }
    }
#pragma unroll
    for (int ct = 0; ct < 4; ++ct)
#pragma unroll
        for (int rg = 0; rg < 4; ++rg) {
            int l = 16 * wave + 4 * q + rg, p = 16 * ct + ln15;
            size_t tI = rowbase + l;
            float xraw = b2f(XBC[tI * DXBC_ + h * HD_ + p]);
            Y[tI * DI_ + h * HD_ + p] = f2b(a2[ct][rg] + Dh * xraw);
        }
    // step 3: st[p][n]
    f32x4 a3[4];
#pragma unroll
    for (int ct = 0; ct < 4; ++ct) a3[ct] = (f32x4){0.f, 0.f, 0.f, 0.f};
#pragma unroll
    for (int ks = 0; ks < 2; ++ks) {
        short8 afr = *(const short8*)&Xt[16 * wave + ln15][ks * 32 + q * 8];
#pragma unroll
        for (int ct = 0; ct < 4; ++ct) {
            short8 bfr = *(const short8*)&Bt[16 * ct + ln15][ks * 32 + q * 8];
            a3[ct] = __builtin_amdgcn_mfma_f32_16x16x32_bf16(afr, bfr, a3[ct], 0, 0, 0);
        }
    }
    size_t sb = ((((size_t)dir * B_ + b) * NC_ + c) * NH_ + h) * 4096;
#pragma unroll
    for (int ct = 0; ct < 4; ++ct)
#pragma unroll
        for (int rg = 0; rg < 4; ++rg) {
            int p = 16 * wave + 4 * q + rg, n = 16 * ct + ln15;
            ST[sb + p * 64 + n] = f2b(a3[ct][rg]);
        }
}

// ---------------------------------------------------------------------------
// K3: inter-chunk scan, in place. grid (256, 2), block 256, 4 els/thread.
// ---------------------------------------------------------------------------
__global__ __launch_bounds__(256) void k_scan(bf16* __restrict__ ST, const float* __restrict__ CDb)
{
    const int tid = threadIdx.x;
    const int dir = blockIdx.y;
    const int bx = blockIdx.x;
    const int b = bx >> 4, h = (bx >> 2) & 3, qt = bx & 3;
    const size_t cdbase = (((size_t)dir * B_ + b) * NH_ + h) * NC_;
    float carry[4] = {0.f, 0.f, 0.f, 0.f};
    for (int c = 0; c < NC_; ++c) {
        const float cd = CDb[cdbase + c];
        size_t base = ((((size_t)dir * B_ + b) * NC_ + c) * NH_ + h) * 4096 + qt * 1024 + tid;
#pragma unroll
        for (int q = 0; q < 4; ++q) {
            float v = b2f(ST[base + q * 256]);
            ST[base + q * 256] = f2b(carry[q]);
            carry[q] = carry[q] * cd + v;
        }
    }
}

// ---------------------------------------------------------------------------
// K4 (MFMA, fused gate+RMSNorm): Yfinal = rmsnorm((Yd + offdiag) * silu(z)) * nw.
// grid: (32, 16, 2), block 256. Yz strictly wave-private; Acs via wave scans.
// ---------------------------------------------------------------------------
__global__ __launch_bounds__(256) void k_offdiag_fused(
    const bf16* __restrict__ XBC, const float* __restrict__ DTV,
    const float* __restrict__ AlF, const float* __restrict__ AlB,
    const bf16* __restrict__ ST, const bf16* __restrict__ Z,
    const float* __restrict__ nwF, const float* __restrict__ nwB,
    bf16* __restrict__ Y)
{
    const int tid = threadIdx.x;
    const int wave = tid >> 6, lane = tid & 63;
    const int ln15 = lane & 15, q = lane >> 4;
    const int c = blockIdx.x, b = blockIdx.y, dir = blockIdx.z;
    const float* Al = dir ? AlB : AlF;
    const int t0 = b * L_ + c * 64;
    const size_t rowbase = (size_t)dir * T_ + t0;

    __shared__ __align__(16) short Cs[64][72];
    __shared__ __align__(16) short Ps[64][72];
    __shared__ __align__(16) short Yz[64][264];
    __shared__ float eA[NH_][64];

    // per-wave shuffle scan: wave w computes eA for head w
    {
        float A = -expf(Al[wave]);
        float s = DTV[(rowbase + lane) * NH_ + wave] * A;
#pragma unroll
        for (int off = 1; off < 64; off <<= 1) {
            float t2 = __shfl_up(s, off);
            if (lane >= off) s += t2;
        }
        eA[wave][lane] = expneg_(s);
    }
    for (int u = tid; u < 512; u += 256) {
        int r = u >> 3, g = u & 7;
        *(short8*)&Cs[r][g * 8] = *(const short8*)(XBC + (rowbase + r) * DXBC_ + 320 + g * 8);
    }
    // stage diag-Y tile, wave-private rows
    for (int u = lane; u < 512; u += 64) {
        int r = 16 * wave + (u >> 5), g = u & 31;
        *(short8*)&Yz[r][g * 8] = *(const short8*)(Y + (rowbase + r) * DI_ + g * 8);
    }

    for (int h = 0; h < NH_; ++h) {
        __syncthreads();   // eA/Cs ready (h=0); prior MFMA's Ps reads done (h>0)
        size_t sb = ((((size_t)dir * B_ + b) * NC_ + c) * NH_ + h) * 4096;
        for (int u = tid; u < 512; u += 256) {
            int r = u >> 3, g = u & 7;
            *(short8*)&Ps[r][g * 8] = *(const short8*)(ST + sb + r * 64 + g * 8);
        }
        __syncthreads();

        f32x4 acc[4];
#pragma unroll
        for (int ct = 0; ct < 4; ++ct) acc[ct] = (f32x4){0.f, 0.f, 0.f, 0.f};
#pragma unroll
        for (int ks = 0; ks < 2; ++ks) {
            short8 afr = *(const short8*)&Cs[16 * wave + ln15][ks * 32 + q * 8];
#pragma unroll
            for (int ct = 0; ct < 4; ++ct) {
                short8 bfr = *(const short8*)&Ps[16 * ct + ln15][ks * 32 + q * 8];
                acc[ct] = __builtin_amdgcn_mfma_f32_16x16x32_bf16(afr, bfr, acc[ct], 0, 0, 0);
            }
        }
#pragma unroll
        for (int ct = 0; ct < 4; ++ct)
#pragma unroll
            for (int rg = 0; rg < 4; ++rg) {
                int l = 16 * wave + 4 * q + rg, p = 16 * ct + ln15;
                float yv = bs2f(Yz[l][h * 64 + p]) + acc[ct][rg] * eA[h][l];
                Yz[l][h * 64 + p] = f2bs(yv);   // own wave rows only
            }
    }

    // gate + RMSNorm epilogue (Yz wave-private: no barrier needed)
    const float* nw = dir ? nwB : nwF;
    float nwv[4];
#pragma unroll
    for (int j = 0; j < 4; ++j) nwv[j] = nw[lane * 4 + j];
    for (int rr = 0; rr < 16; ++rr) {
        int row = 16 * wave + rr;
        S4 zv4 = *(const S4*)(Z + (rowbase + row) * DI_ + lane * 4);
        short zr[4] = { zv4.a, zv4.b, zv4.c, zv4.d };
        float v[4]; float ss = 0.f;
#pragma unroll
        for (int j = 0; j < 4; ++j) {
            float yv = bs2f(Yz[row][lane * 4 + j]);
            float zf = bs2f(zr[j]);
            v[j] = yv * zf * sigmoidf_(zf);
            ss += v[j] * v[j];
        }
#pragma unroll
        for (int off = 1; off < 64; off <<= 1) ss += __shfl_xor(ss, off);
        float rn = rsqrtf(ss * (1.f / 256.f) + 1e-5f);
        S4 o = { f2bs(v[0] * rn * nwv[0]), f2bs(v[1] * rn * nwv[1]),
                 f2bs(v[2] * rn * nwv[2]), f2bs(v[3] * rn * nwv[3]) };
        *(S4*)(Y + (rowbase + row) * DI_ + lane * 4) = o;
    }
}

// ---------------------------------------------------------------------------
// K6 (MFMA): out[t] = y_f[t] @ Wo_f^T + y_b[flip(t)] @ Wo_b^T.
// grid 512, block 512 (8 waves: 4 M-strips x 2 N-halves).
// ---------------------------------------------------------------------------
__global__ __launch_bounds__(512) void k_outproj_mfma(
    const bf16* __restrict__ Y, const bf16* __restrict__ WoFb, const bf16* __restrict__ WoBb,
    float* __restrict__ out)
{
    const int tid = threadIdx.x;
    const int wave = tid >> 6, lane = tid & 63;
    const int ln15 = lane & 15, q = lane >> 4;
    const int mt = wave & 3, nh = wave >> 2;
    const int t0 = blockIdx.x * 64;
    const int batch = t0 >> 11;
    const int l0 = t0 & (L_ - 1);

    __shared__ __align__(16) short ys[64][72];
    __shared__ __align__(16) short wsm[128][72];

    f32x4 acc[4];
#pragma unroll
    for (int ct = 0; ct < 4; ++ct) acc[ct] = (f32x4){0.f, 0.f, 0.f, 0.f};

    for (int dir = 0; dir < 2; ++dir) {
        const bf16* Wo = dir ? WoBb : WoFb;
        for (int kt = 0; kt < 4; ++kt) {
            const int k0 = kt * 64;
            __syncthreads();
            {
                int u = tid;   // 512 entries, one per thread
                int r = u >> 3, g = u & 7;
                int tsrc = dir ? (batch * L_ + (L_ - 1 - (l0 + r))) : (t0 + r);
                *(short8*)&ys[r][g * 8] =
                    *(const short8*)(Y + ((size_t)dir * T_ + tsrc) * DI_ + k0 + g * 8);
            }
            for (int u = tid; u < 1024; u += 512) {
                int m = u >> 3, g = u & 7;
                *(short8*)&wsm[m][g * 8] = *(const short8*)(Wo + (size_t)m * DI_ + k0 + g * 8);
            }
            __syncthreads();
#pragma unroll
            for (int ks = 0; ks < 2; ++ks) {
                short8 afr = *(const short8*)&ys[16 * mt + ln15][ks * 32 + q * 8];
#pragma unroll
                for (int ct = 0; ct < 4; ++ct) {
                    short8 bfr = *(const short8*)&wsm[16 * (4 * nh + ct) + ln15][ks * 32 + q * 8];
                    acc[ct] = __builtin_amdgcn_mfma_f32_16x16x32_bf16(afr, bfr, acc[ct], 0, 0, 0);
                }
            }
        }
    }
#pragma unroll
    for (int ct = 0; ct < 4; ++ct)
#pragma unroll
        for (int rg = 0; rg < 4; ++rg) {
            int row = 16 * mt + 4 * q + rg, col = 16 * (4 * nh + ct) + ln15;
            out[((size_t)(t0 + row)) * DM_ + col] = acc[ct][rg];
        }
}

// ---------------------------------------------------------------------------
extern "C" void kernel_launch(void* const* d_in, const int* in_sizes, int n_in,
                              void* d_out, int out_size, void* d_ws, size_t ws_size,
                              hipStream_t stream)
{
    const float* x    = (const float*)d_in[0];
    const float* WiF  = (const float*)d_in[1];
    const float* cwF  = (const float*)d_in[2];
    const float* cbF  = (const float*)d_in[3];
    const float* dtbF = (const float*)d_in[4];
    const float* AlF  = (const float*)d_in[5];
    const float* DpF  = (const float*)d_in[6];
    const float* nwF  = (const float*)d_in[7];
    const float* WoF  = (const float*)d_in[8];
    const float* WiB  = (const float*)d_in[9];
    const float* cwB  = (const float*)d_in[10];
    const float* cbB  = (const float*)d_in[11];
    const float* dtbB = (const float*)d_in[12];
    const float* AlB  = (const float*)d_in[13];
    const float* DpB  = (const float*)d_in[14];
    const float* nwB  = (const float*)d_in[15];
    const float* WoB  = (const float*)d_in[16];

    const size_t nZ   = (size_t)2 * T_ * DI_;       // bf16
    const size_t nXBC = (size_t)2 * T_ * DXBC_;     // bf16
    const size_t nY   = (size_t)2 * T_ * DI_;       // bf16
    const size_t nST  = (size_t)2 * B_ * NC_ * NH_ * HD_ * DS_;  // bf16
    const size_t nWb  = (size_t)2 * NWI + 2 * NWO;  // bf16 weight copies
    const size_t nDTV = (size_t)2 * T_ * NH_;       // f32
    const size_t nCD  = (size_t)2 * B_ * NH_ * NC_; // f32
    const size_t need = (nZ + nXBC + nY + nST + nWb) * sizeof(bf16)
                      + (nDTV + nCD) * sizeof(float);
    if (ws_size < need) return;

    char* p = (char*)d_ws;
    bf16* Z    = (bf16*)p;            p += nZ * sizeof(bf16);
    bf16* XBC  = (bf16*)p;            p += nXBC * sizeof(bf16);
    bf16* Yb   = (bf16*)p;            p += nY * sizeof(bf16);
    bf16* ST   = (bf16*)p;            p += nST * sizeof(bf16);
    bf16* WiFb = (bf16*)p;            p += (size_t)NWI * sizeof(bf16);
    bf16* WiBb = (bf16*)p;            p += (size_t)NWI * sizeof(bf16);
    bf16* WoFb = (bf16*)p;            p += (size_t)NWO * sizeof(bf16);
    bf16* WoBb = (bf16*)p;            p += (size_t)NWO * sizeof(bf16);
    float* DTV = (float*)p;           p += nDTV * sizeof(float);
    float* CDb = (float*)p;
    bf16* Xb   = ST;   // alias: Xb dead before ST is written (k_chunkdiag)

    k_prep<<<2048, 256, 0, stream>>>(x, WiF, WiB, WoF, WoB, Xb, WiFb, WiBb, WoFb, WoBb);
    k_inproj_mfma<<<dim3(512, 2), 256, 0, stream>>>(Xb, WiFb, WiBb, cwF, cbF, cwB, cbB,
                                                    dtbF, dtbB, Z, XBC, DTV);
    k_chunkdiag_mfma<<<dim3(NC_, B_ * NH_, 2), 256, 0, stream>>>(XBC, DTV, AlF, AlB, DpF, DpB,
                                                                 Yb, ST, CDb);
    k_scan<<<dim3(256, 2), 256, 0, stream>>>(ST, CDb);
    k_offdiag_fused<<<dim3(NC_, B_, 2), 256, 0, stream>>>(XBC, DTV, AlF, AlB, ST, Z,
                                                          nwF, nwB, Yb);
    k_outproj_mfma<<<dim3(512), 512, 0, stream>>>(Yb, WoFb, WoBb, (float*)d_out);
}